// Round 3
// baseline (790.654 us; speedup 1.0000x reference)
//
#include <hip/hip_runtime.h>

constexpr int NN = 50000;    // nodes
constexpr int NE = 1600000;  // edges
constexpr int NG = 128;      // graphs

// workspace layout (bytes); all offsets 16B-aligned
#define OFF_DEG      0            // int[50000]
#define OFF_GSUM     200000       // float[128*20]
#define OFF_GCNT     210240       // float[128]
#define ZERO_BYTES   210752
#define OFF_ROWSTART 210752       // int[50000]
#define OFF_CURSOR   410752       // int[50000]
#define OFF_ADJ      610752       // int[1600000]
#define OFF_X1       7010752      // float[50000*100] = feat@W1
#define OFF_H1       27010752     // float[50000*100] = relu layer1
#define OFF_X2       47010752     // float[50000*20]  = H1@W2
// end: 51010752 bytes (~51 MB)

// ---- in-degree histogram -------------------------------------------------
__global__ void k_deg(const int* __restrict__ dst, int* __restrict__ deg) {
    int i = blockIdx.x * blockDim.x + threadIdx.x;
    if (i < NE) atomicAdd(&deg[dst[i]], 1);
}

// ---- exclusive scan of deg -> rowstart (and cursor copy), single block ----
__global__ __launch_bounds__(1024) void k_scan(const int* __restrict__ deg,
                                               int* __restrict__ rowstart,
                                               int* __restrict__ cursor) {
    __shared__ int sums[1024];
    const int t = threadIdx.x;
    const int chunk = (NN + 1023) / 1024;   // 49
    const int lo = t * chunk;
    const int hi = min(lo + chunk, NN);
    int s = 0;
    for (int i = lo; i < hi; ++i) s += deg[i];
    sums[t] = s;
    __syncthreads();
    // Hillis-Steele inclusive scan over 1024 partials
    for (int off = 1; off < 1024; off <<= 1) {
        int v = (t >= off) ? sums[t - off] : 0;
        __syncthreads();
        sums[t] += v;
        __syncthreads();
    }
    int run = (t > 0) ? sums[t - 1] : 0;    // exclusive prefix for this chunk
    for (int i = lo; i < hi; ++i) {
        rowstart[i] = run;
        cursor[i]   = run;
        run += deg[i];
    }
}

// ---- CSR fill: adj holds src node of every in-edge, grouped by dst --------
__global__ void k_fill(const int* __restrict__ src, const int* __restrict__ dst,
                       int* __restrict__ cursor, int* __restrict__ adj) {
    int i = blockIdx.x * blockDim.x + threadIdx.x;
    if (i < NE) {
        int p = atomicAdd(&cursor[dst[i]], 1);
        adj[p] = src[i];
    }
}

// ---- X1 = feat @ W1  (50000x128 @ 128x100), no bias yet -------------------
// Register-tiled: thread = 4 nodes x 4 cols (16 acc), K blocked by 4 so both
// operands are float4 loads. Block 256 (250 active): cg=t%25 (col quad),
// nq=t/25 (node quad 0..9) -> 40 nodes/block, grid 1250.
__global__ __launch_bounds__(256) void k_gemm1(const float4* __restrict__ feat4,
                                               const float* __restrict__ W1,
                                               float* __restrict__ X1) {
    const int t = threadIdx.x;
    if (t >= 250) return;
    const int cg = t % 25;            // cols [4cg, 4cg+4)
    const int nq = t / 25;            // node quad within block
    const int node0 = blockIdx.x * 40 + nq * 4;
    const int col0 = cg * 4;

    float acc[4][4];
#pragma unroll
    for (int i = 0; i < 4; ++i)
#pragma unroll
        for (int j = 0; j < 4; ++j) acc[i][j] = 0.f;

    for (int k4 = 0; k4 < 32; ++k4) {
        float4 f[4];
#pragma unroll
        for (int i = 0; i < 4; ++i) f[i] = feat4[(node0 + i) * 32 + k4];
        float4 wr[4];
#pragma unroll
        for (int kk = 0; kk < 4; ++kk)
            wr[kk] = *(const float4*)(W1 + (k4 * 4 + kk) * 100 + col0);
#pragma unroll
        for (int kk = 0; kk < 4; ++kk) {
#pragma unroll
            for (int i = 0; i < 4; ++i) {
                const float fv = (kk == 0) ? f[i].x
                               : (kk == 1) ? f[i].y
                               : (kk == 2) ? f[i].z : f[i].w;
                acc[i][0] += fv * wr[kk].x;
                acc[i][1] += fv * wr[kk].y;
                acc[i][2] += fv * wr[kk].z;
                acc[i][3] += fv * wr[kk].w;
            }
        }
    }
#pragma unroll
    for (int i = 0; i < 4; ++i) {
        float4 r;
        r.x = acc[i][0]; r.y = acc[i][1]; r.z = acc[i][2]; r.w = acc[i][3];
        *(float4*)(X1 + (node0 + i) * 100 + col0) = r;
    }
}

// ---- layer-1 aggregate: H1 = relu(where(deg>0, mean(X1[adj]), X1) + b1) ---
// Thread per (node, q), q = one float4 of the 100-dim row (25 per node).
// Edge loop unrolled x4 with independent accumulators: 4 outstanding gathers
// per thread (MLP), no change in traffic.
__global__ void k_agg1(const float4* __restrict__ X1v, const int* __restrict__ rowstart,
                       const int* __restrict__ deg, const int* __restrict__ adj,
                       const float4* __restrict__ b1v, float4* __restrict__ H1v) {
    int tid = blockIdx.x * blockDim.x + threadIdx.x;
    if (tid >= NN * 25) return;
    const int node = tid / 25;
    const int q = tid - node * 25;
    const int rs = rowstart[node];
    const int d = deg[node];
    float ax0 = 0.f, ay0 = 0.f, az0 = 0.f, aw0 = 0.f;
    float ax1 = 0.f, ay1 = 0.f, az1 = 0.f, aw1 = 0.f;
    float ax2 = 0.f, ay2 = 0.f, az2 = 0.f, aw2 = 0.f;
    float ax3 = 0.f, ay3 = 0.f, az3 = 0.f, aw3 = 0.f;
    int i = 0;
    for (; i + 4 <= d; i += 4) {
        const int s0 = adj[rs + i + 0];
        const int s1 = adj[rs + i + 1];
        const int s2 = adj[rs + i + 2];
        const int s3 = adj[rs + i + 3];
        const float4 v0 = X1v[s0 * 25 + q];
        const float4 v1 = X1v[s1 * 25 + q];
        const float4 v2 = X1v[s2 * 25 + q];
        const float4 v3 = X1v[s3 * 25 + q];
        ax0 += v0.x; ay0 += v0.y; az0 += v0.z; aw0 += v0.w;
        ax1 += v1.x; ay1 += v1.y; az1 += v1.z; aw1 += v1.w;
        ax2 += v2.x; ay2 += v2.y; az2 += v2.z; aw2 += v2.w;
        ax3 += v3.x; ay3 += v3.y; az3 += v3.z; aw3 += v3.w;
    }
    for (; i < d; ++i) {
        const int s = adj[rs + i];
        const float4 v = X1v[s * 25 + q];
        ax0 += v.x; ay0 += v.y; az0 += v.z; aw0 += v.w;
    }
    float ax = (ax0 + ax1) + (ax2 + ax3);
    float ay = (ay0 + ay1) + (ay2 + ay3);
    float az = (az0 + az1) + (az2 + az3);
    float aw = (aw0 + aw1) + (aw2 + aw3);
    if (d > 0) {
        const float inv = 1.f / (float)d;
        ax *= inv; ay *= inv; az *= inv; aw *= inv;
    } else {
        const float4 v = X1v[node * 25 + q];
        ax = v.x; ay = v.y; az = v.z; aw = v.w;
    }
    const float4 b = b1v[q];
    float4 r;
    r.x = fmaxf(ax + b.x, 0.f);
    r.y = fmaxf(ay + b.y, 0.f);
    r.z = fmaxf(az + b.z, 0.f);
    r.w = fmaxf(aw + b.w, 0.f);
    H1v[tid] = r;   // tid == node*25+q
}

// ---- X2 = H1 @ W2  (50000x100 @ 100x20), no bias yet ----------------------
__global__ void k_gemm2(const float* __restrict__ H1, const float* __restrict__ W2,
                        float* __restrict__ X2) {
    int tid = blockIdx.x * blockDim.x + threadIdx.x;
    if (tid >= NN * 20) return;
    const int node = tid / 20;
    const int j = tid - node * 20;
    const float* h = H1 + node * 100;
    float acc = 0.f;
#pragma unroll 5
    for (int k = 0; k < 100; ++k) acc += h[k] * W2[k * 20 + j];
    X2[tid] = acc;   // coalesced: tid == node*20+j
}

// ---- layer-2 aggregate + per-graph accumulate -----------------------------
// Thread per (node, q), q = one float4 of the 20-dim row (5 per node).
// Edge loop unrolled x8 (8 outstanding gathers/thread): only 250K threads,
// so per-thread MLP has to carry the latency hiding.
__global__ void k_agg2(const float4* __restrict__ X2v, const int* __restrict__ rowstart,
                       const int* __restrict__ deg, const int* __restrict__ adj,
                       const float4* __restrict__ b2v, const int* __restrict__ graph_id,
                       float* __restrict__ g_sum, float* __restrict__ g_cnt) {
    int tid = blockIdx.x * blockDim.x + threadIdx.x;
    if (tid >= NN * 5) return;
    const int node = tid / 5;
    const int q = tid - node * 5;
    const int rs = rowstart[node];
    const int d = deg[node];
    float ax0 = 0.f, ay0 = 0.f, az0 = 0.f, aw0 = 0.f;
    float ax1 = 0.f, ay1 = 0.f, az1 = 0.f, aw1 = 0.f;
    float ax2 = 0.f, ay2 = 0.f, az2 = 0.f, aw2 = 0.f;
    float ax3 = 0.f, ay3 = 0.f, az3 = 0.f, aw3 = 0.f;
    int i = 0;
    for (; i + 8 <= d; i += 8) {
        const int s0 = adj[rs + i + 0];
        const int s1 = adj[rs + i + 1];
        const int s2 = adj[rs + i + 2];
        const int s3 = adj[rs + i + 3];
        const int s4 = adj[rs + i + 4];
        const int s5 = adj[rs + i + 5];
        const int s6 = adj[rs + i + 6];
        const int s7 = adj[rs + i + 7];
        const float4 v0 = X2v[s0 * 5 + q];
        const float4 v1 = X2v[s1 * 5 + q];
        const float4 v2 = X2v[s2 * 5 + q];
        const float4 v3 = X2v[s3 * 5 + q];
        const float4 v4 = X2v[s4 * 5 + q];
        const float4 v5 = X2v[s5 * 5 + q];
        const float4 v6 = X2v[s6 * 5 + q];
        const float4 v7 = X2v[s7 * 5 + q];
        ax0 += v0.x; ay0 += v0.y; az0 += v0.z; aw0 += v0.w;
        ax1 += v1.x; ay1 += v1.y; az1 += v1.z; aw1 += v1.w;
        ax2 += v2.x; ay2 += v2.y; az2 += v2.z; aw2 += v2.w;
        ax3 += v3.x; ay3 += v3.y; az3 += v3.z; aw3 += v3.w;
        ax0 += v4.x; ay0 += v4.y; az0 += v4.z; aw0 += v4.w;
        ax1 += v5.x; ay1 += v5.y; az1 += v5.z; aw1 += v5.w;
        ax2 += v6.x; ay2 += v6.y; az2 += v6.z; aw2 += v6.w;
        ax3 += v7.x; ay3 += v7.y; az3 += v7.z; aw3 += v7.w;
    }
    for (; i < d; ++i) {
        const int s = adj[rs + i];
        const float4 v = X2v[s * 5 + q];
        ax0 += v.x; ay0 += v.y; az0 += v.z; aw0 += v.w;
    }
    float ax = (ax0 + ax1) + (ax2 + ax3);
    float ay = (ay0 + ay1) + (ay2 + ay3);
    float az = (az0 + az1) + (az2 + az3);
    float aw = (aw0 + aw1) + (aw2 + aw3);
    if (d > 0) {
        const float inv = 1.f / (float)d;
        ax *= inv; ay *= inv; az *= inv; aw *= inv;
    } else {
        const float4 v = X2v[node * 5 + q];
        ax = v.x; ay = v.y; az = v.z; aw = v.w;
    }
    const float4 b = b2v[q];
    const float hx = fmaxf(ax + b.x, 0.f);
    const float hy = fmaxf(ay + b.y, 0.f);
    const float hz = fmaxf(az + b.z, 0.f);
    const float hw = fmaxf(aw + b.w, 0.f);
    const int g = graph_id[node];
    float* gs = g_sum + g * 20 + q * 4;
    atomicAdd(gs + 0, hx);
    atomicAdd(gs + 1, hy);
    atomicAdd(gs + 2, hz);
    atomicAdd(gs + 3, hw);
    if (q == 0) atomicAdd(&g_cnt[g], 1.f);
}

// ---- final: hg = g_sum/max(cnt,1); out = relu([hg,self]@Wf1+bf1)@Wf2+bf2 --
__global__ __launch_bounds__(128) void k_final(const float* __restrict__ g_sum,
                                               const float* __restrict__ g_cnt,
                                               const float* __restrict__ self_feat,
                                               const float* __restrict__ Wf1,
                                               const float* __restrict__ bf1,
                                               const float* __restrict__ Wf2,
                                               const float* __restrict__ bf2,
                                               float* __restrict__ out) {
    const int g = threadIdx.x;  // 128 graphs, one block
    float fused[36];
    const float cnt = fmaxf(g_cnt[g], 1.f);
    const float inv = 1.f / cnt;
#pragma unroll
    for (int j = 0; j < 20; ++j) fused[j] = g_sum[g * 20 + j] * inv;
#pragma unroll
    for (int j = 0; j < 16; ++j) fused[20 + j] = self_feat[g * 16 + j];
    float o = bf2[0];
#pragma unroll
    for (int i = 0; i < 10; ++i) {
        float t = bf1[i];
#pragma unroll
        for (int k = 0; k < 36; ++k) t += fused[k] * Wf1[k * 10 + i];
        o += fmaxf(t, 0.f) * Wf2[i];
    }
    out[g] = o;
}

extern "C" void kernel_launch(void* const* d_in, const int* in_sizes, int n_in,
                              void* d_out, int out_size, void* d_ws, size_t ws_size,
                              hipStream_t stream) {
    const float* feat      = (const float*)d_in[0];
    const float* self_feat = (const float*)d_in[1];
    const int*   src       = (const int*)d_in[2];
    const int*   dst       = (const int*)d_in[3];
    const int*   graph_id  = (const int*)d_in[4];
    const float* W1        = (const float*)d_in[5];
    const float* b1        = (const float*)d_in[6];
    const float* W2        = (const float*)d_in[7];
    const float* b2        = (const float*)d_in[8];
    const float* Wf1       = (const float*)d_in[9];
    const float* bf1       = (const float*)d_in[10];
    const float* Wf2       = (const float*)d_in[11];
    const float* bf2       = (const float*)d_in[12];

    char* w = (char*)d_ws;
    int*   deg      = (int*)(w + OFF_DEG);
    float* g_sum    = (float*)(w + OFF_GSUM);
    float* g_cnt    = (float*)(w + OFF_GCNT);
    int*   rowstart = (int*)(w + OFF_ROWSTART);
    int*   cursor   = (int*)(w + OFF_CURSOR);
    int*   adj      = (int*)(w + OFF_ADJ);
    float* X1       = (float*)(w + OFF_X1);
    float* H1       = (float*)(w + OFF_H1);
    float* X2       = (float*)(w + OFF_X2);

    hipMemsetAsync(w, 0, ZERO_BYTES, stream);  // deg + g_sum + g_cnt

    k_deg<<<(NE + 255) / 256, 256, 0, stream>>>(dst, deg);
    k_scan<<<1, 1024, 0, stream>>>(deg, rowstart, cursor);
    k_fill<<<(NE + 255) / 256, 256, 0, stream>>>(src, dst, cursor, adj);
    k_gemm1<<<1250, 256, 0, stream>>>((const float4*)feat, W1, X1);
    k_agg1<<<(NN * 25 + 255) / 256, 256, 0, stream>>>((const float4*)X1, rowstart, deg,
                                                      adj, (const float4*)b1, (float4*)H1);
    k_gemm2<<<(NN * 20 + 255) / 256, 256, 0, stream>>>(H1, W2, X2);
    k_agg2<<<(NN * 5 + 255) / 256, 256, 0, stream>>>((const float4*)X2, rowstart, deg,
                                                     adj, (const float4*)b2, graph_id,
                                                     g_sum, g_cnt);
    k_final<<<1, 128, 0, stream>>>(g_sum, g_cnt, self_feat, Wf1, bf1, Wf2, bf2,
                                   (float*)d_out);
}

// Round 4
// 729.446 us; speedup vs baseline: 1.0839x; 1.0839x over previous
//
#include <hip/hip_runtime.h>

constexpr int NN = 50000;    // nodes
constexpr int NE = 1600000;  // edges
constexpr int NG = 128;      // graphs

// workspace layout (bytes); all offsets 16B-aligned
#define OFF_DEG      0            // int[50000]
#define OFF_GSUM     200000       // float[128*20]
#define OFF_GCNT     210240       // float[128]
#define ZERO_BYTES   210752
#define OFF_ROWSTART 210752       // int[50000]
#define OFF_CURSOR   410752       // int[50000]
#define OFF_ADJ      610752       // int[1600000]
#define OFF_X1B      7010752      // bf16[50000*128] = feat@W1, row-padded to 128 (2 lines)
#define OFF_H1       19810752     // float[50000*100] = relu layer1
#define OFF_X2       39810752     // float[50000*32]  = H1@W2, row-padded to 32 (1 line)
// end: 46210752 bytes (~46 MB)

// ---- bf16 helpers ---------------------------------------------------------
__device__ __forceinline__ unsigned short f2bf(float x) {      // RNE
    unsigned int v = __float_as_uint(x);
    return (unsigned short)((v + 0x7FFFu + ((v >> 16) & 1u)) >> 16);
}
__device__ __forceinline__ float bflo(unsigned int u) { return __uint_as_float(u << 16); }
__device__ __forceinline__ float bfhi(unsigned int u) { return __uint_as_float(u & 0xFFFF0000u); }

// ---- in-degree histogram -------------------------------------------------
__global__ void k_deg(const int* __restrict__ dst, int* __restrict__ deg) {
    int i = blockIdx.x * blockDim.x + threadIdx.x;
    if (i < NE) atomicAdd(&deg[dst[i]], 1);
}

// ---- exclusive scan of deg -> rowstart (and cursor copy), single block ----
__global__ __launch_bounds__(1024) void k_scan(const int* __restrict__ deg,
                                               int* __restrict__ rowstart,
                                               int* __restrict__ cursor) {
    __shared__ int sums[1024];
    const int t = threadIdx.x;
    const int chunk = (NN + 1023) / 1024;   // 49
    const int lo = t * chunk;
    const int hi = min(lo + chunk, NN);
    int s = 0;
    for (int i = lo; i < hi; ++i) s += deg[i];
    sums[t] = s;
    __syncthreads();
    for (int off = 1; off < 1024; off <<= 1) {
        int v = (t >= off) ? sums[t - off] : 0;
        __syncthreads();
        sums[t] += v;
        __syncthreads();
    }
    int run = (t > 0) ? sums[t - 1] : 0;
    for (int i = lo; i < hi; ++i) {
        rowstart[i] = run;
        cursor[i]   = run;
        run += deg[i];
    }
}

// ---- CSR fill: adj holds src node of every in-edge, grouped by dst --------
__global__ void k_fill(const int* __restrict__ src, const int* __restrict__ dst,
                       int* __restrict__ cursor, int* __restrict__ adj) {
    int i = blockIdx.x * blockDim.x + threadIdx.x;
    if (i < NE) {
        int p = atomicAdd(&cursor[dst[i]], 1);
        adj[p] = src[i];
    }
}

// ---- X1 = bf16(feat @ W1)  (50000x128 @ 128x100), row stride 128 ---------
// Register-tiled: thread = 4 nodes x 4 cols, K blocked by 4 (float4 loads).
__global__ __launch_bounds__(256) void k_gemm1(const float4* __restrict__ feat4,
                                               const float* __restrict__ W1,
                                               unsigned short* __restrict__ X1b) {
    const int t = threadIdx.x;
    if (t >= 250) return;
    const int cg = t % 25;            // cols [4cg, 4cg+4)
    const int nq = t / 25;            // node quad within block
    const int node0 = blockIdx.x * 40 + nq * 4;
    const int col0 = cg * 4;

    float acc[4][4];
#pragma unroll
    for (int i = 0; i < 4; ++i)
#pragma unroll
        for (int j = 0; j < 4; ++j) acc[i][j] = 0.f;

    for (int k4 = 0; k4 < 32; ++k4) {
        float4 f[4];
#pragma unroll
        for (int i = 0; i < 4; ++i) f[i] = feat4[(node0 + i) * 32 + k4];
        float4 wr[4];
#pragma unroll
        for (int kk = 0; kk < 4; ++kk)
            wr[kk] = *(const float4*)(W1 + (k4 * 4 + kk) * 100 + col0);
#pragma unroll
        for (int kk = 0; kk < 4; ++kk) {
#pragma unroll
            for (int i = 0; i < 4; ++i) {
                const float fv = (kk == 0) ? f[i].x
                               : (kk == 1) ? f[i].y
                               : (kk == 2) ? f[i].z : f[i].w;
                acc[i][0] += fv * wr[kk].x;
                acc[i][1] += fv * wr[kk].y;
                acc[i][2] += fv * wr[kk].z;
                acc[i][3] += fv * wr[kk].w;
            }
        }
    }
#pragma unroll
    for (int i = 0; i < 4; ++i) {
        ushort4 r;
        r.x = f2bf(acc[i][0]); r.y = f2bf(acc[i][1]);
        r.z = f2bf(acc[i][2]); r.w = f2bf(acc[i][3]);
        *(ushort4*)(X1b + (node0 + i) * 128 + col0) = r;
        if (cg == 24) {  // zero pad cols 100..103 (read by agg1 lane q=12)
            ushort4 z; z.x = z.y = z.z = z.w = 0;
            *(ushort4*)(X1b + (node0 + i) * 128 + 100) = z;
        }
    }
}

// ---- layer-1 aggregate: H1 = relu(where(deg>0, mean(bf16row), bf16row)+b1)
// 13 lanes per node, lane q loads 16B (8 bf16) of the 256B row: 2 aligned
// lines per edge-row. Serial edge loop (system is request-throughput bound).
__global__ void k_agg1(const uint4* __restrict__ X1u, const int* __restrict__ rowstart,
                       const int* __restrict__ deg, const int* __restrict__ adj,
                       const float* __restrict__ b1, float* __restrict__ H1) {
    int tid = blockIdx.x * blockDim.x + threadIdx.x;
    if (tid >= NN * 13) return;
    const int node = tid / 13;
    const int q = tid - node * 13;        // cols [8q, 8q+8)
    const int rs = rowstart[node];
    const int d = deg[node];
    float a0 = 0.f, a1 = 0.f, a2 = 0.f, a3 = 0.f;
    float a4 = 0.f, a5 = 0.f, a6 = 0.f, a7 = 0.f;
    for (int i = 0; i < d; ++i) {
        const int s = adj[rs + i];          // broadcast across the 13-lane group
        const uint4 u = X1u[s * 16 + q];    // 16B of the 256B row
        a0 += bflo(u.x); a1 += bfhi(u.x);
        a2 += bflo(u.y); a3 += bfhi(u.y);
        a4 += bflo(u.z); a5 += bfhi(u.z);
        a6 += bflo(u.w); a7 += bfhi(u.w);
    }
    if (d > 0) {
        const float inv = 1.f / (float)d;
        a0 *= inv; a1 *= inv; a2 *= inv; a3 *= inv;
        a4 *= inv; a5 *= inv; a6 *= inv; a7 *= inv;
    } else {
        const uint4 u = X1u[node * 16 + q];
        a0 = bflo(u.x); a1 = bfhi(u.x);
        a2 = bflo(u.y); a3 = bfhi(u.y);
        a4 = bflo(u.z); a5 = bfhi(u.z);
        a6 = bflo(u.w); a7 = bfhi(u.w);
    }
    const int col0 = 8 * q;
    float4 r0;
    r0.x = fmaxf(a0 + b1[col0 + 0], 0.f);
    r0.y = fmaxf(a1 + b1[col0 + 1], 0.f);
    r0.z = fmaxf(a2 + b1[col0 + 2], 0.f);
    r0.w = fmaxf(a3 + b1[col0 + 3], 0.f);
    *(float4*)(H1 + node * 100 + col0) = r0;
    if (q < 12) {                          // cols 100..103 are pad, skip
        float4 r1;
        r1.x = fmaxf(a4 + b1[col0 + 4], 0.f);
        r1.y = fmaxf(a5 + b1[col0 + 5], 0.f);
        r1.z = fmaxf(a6 + b1[col0 + 6], 0.f);
        r1.w = fmaxf(a7 + b1[col0 + 7], 0.f);
        *(float4*)(H1 + node * 100 + col0 + 4) = r1;
    }
}

// ---- X2 = H1 @ W2  (50000x100 @ 100x20), row stride 32 (1 line/row) ------
__global__ void k_gemm2(const float* __restrict__ H1, const float* __restrict__ W2,
                        float* __restrict__ X2) {
    int tid = blockIdx.x * blockDim.x + threadIdx.x;
    if (tid >= NN * 20) return;
    const int node = tid / 20;
    const int j = tid - node * 20;
    const float* h = H1 + node * 100;
    float acc = 0.f;
#pragma unroll 5
    for (int k = 0; k < 100; ++k) acc += h[k] * W2[k * 20 + j];
    X2[node * 32 + j] = acc;
}

// ---- layer-2 aggregate + per-graph accumulate -----------------------------
// 5 lanes per node, lane q loads one float4 of the 128B-aligned row:
// exactly 1 line per edge-row. Serial edge loop.
__global__ void k_agg2(const float4* __restrict__ X2v, const int* __restrict__ rowstart,
                       const int* __restrict__ deg, const int* __restrict__ adj,
                       const float4* __restrict__ b2v, const int* __restrict__ graph_id,
                       float* __restrict__ g_sum, float* __restrict__ g_cnt) {
    int tid = blockIdx.x * blockDim.x + threadIdx.x;
    if (tid >= NN * 5) return;
    const int node = tid / 5;
    const int q = tid - node * 5;
    const int rs = rowstart[node];
    const int d = deg[node];
    float ax = 0.f, ay = 0.f, az = 0.f, aw = 0.f;
    for (int i = 0; i < d; ++i) {
        const int s = adj[rs + i];
        const float4 v = X2v[s * 8 + q];    // row stride 8 float4s (128B)
        ax += v.x; ay += v.y; az += v.z; aw += v.w;
    }
    if (d > 0) {
        const float inv = 1.f / (float)d;
        ax *= inv; ay *= inv; az *= inv; aw *= inv;
    } else {
        const float4 v = X2v[node * 8 + q];
        ax = v.x; ay = v.y; az = v.z; aw = v.w;
    }
    const float4 b = b2v[q];
    const float hx = fmaxf(ax + b.x, 0.f);
    const float hy = fmaxf(ay + b.y, 0.f);
    const float hz = fmaxf(az + b.z, 0.f);
    const float hw = fmaxf(aw + b.w, 0.f);
    const int g = graph_id[node];
    float* gs = g_sum + g * 20 + q * 4;
    atomicAdd(gs + 0, hx);
    atomicAdd(gs + 1, hy);
    atomicAdd(gs + 2, hz);
    atomicAdd(gs + 3, hw);
    if (q == 0) atomicAdd(&g_cnt[g], 1.f);
}

// ---- final: hg = g_sum/max(cnt,1); out = relu([hg,self]@Wf1+bf1)@Wf2+bf2 --
__global__ __launch_bounds__(128) void k_final(const float* __restrict__ g_sum,
                                               const float* __restrict__ g_cnt,
                                               const float* __restrict__ self_feat,
                                               const float* __restrict__ Wf1,
                                               const float* __restrict__ bf1,
                                               const float* __restrict__ Wf2,
                                               const float* __restrict__ bf2,
                                               float* __restrict__ out) {
    const int g = threadIdx.x;  // 128 graphs, one block
    float fused[36];
    const float cnt = fmaxf(g_cnt[g], 1.f);
    const float inv = 1.f / cnt;
#pragma unroll
    for (int j = 0; j < 20; ++j) fused[j] = g_sum[g * 20 + j] * inv;
#pragma unroll
    for (int j = 0; j < 16; ++j) fused[20 + j] = self_feat[g * 16 + j];
    float o = bf2[0];
#pragma unroll
    for (int i = 0; i < 10; ++i) {
        float t = bf1[i];
#pragma unroll
        for (int k = 0; k < 36; ++k) t += fused[k] * Wf1[k * 10 + i];
        o += fmaxf(t, 0.f) * Wf2[i];
    }
    out[g] = o;
}

extern "C" void kernel_launch(void* const* d_in, const int* in_sizes, int n_in,
                              void* d_out, int out_size, void* d_ws, size_t ws_size,
                              hipStream_t stream) {
    const float* feat      = (const float*)d_in[0];
    const float* self_feat = (const float*)d_in[1];
    const int*   src       = (const int*)d_in[2];
    const int*   dst       = (const int*)d_in[3];
    const int*   graph_id  = (const int*)d_in[4];
    const float* W1        = (const float*)d_in[5];
    const float* b1        = (const float*)d_in[6];
    const float* W2        = (const float*)d_in[7];
    const float* b2        = (const float*)d_in[8];
    const float* Wf1       = (const float*)d_in[9];
    const float* bf1       = (const float*)d_in[10];
    const float* Wf2       = (const float*)d_in[11];
    const float* bf2       = (const float*)d_in[12];

    char* w = (char*)d_ws;
    int*            deg      = (int*)(w + OFF_DEG);
    float*          g_sum    = (float*)(w + OFF_GSUM);
    float*          g_cnt    = (float*)(w + OFF_GCNT);
    int*            rowstart = (int*)(w + OFF_ROWSTART);
    int*            cursor   = (int*)(w + OFF_CURSOR);
    int*            adj      = (int*)(w + OFF_ADJ);
    unsigned short* X1b      = (unsigned short*)(w + OFF_X1B);
    float*          H1       = (float*)(w + OFF_H1);
    float*          X2       = (float*)(w + OFF_X2);

    hipMemsetAsync(w, 0, ZERO_BYTES, stream);  // deg + g_sum + g_cnt

    k_deg<<<(NE + 255) / 256, 256, 0, stream>>>(dst, deg);
    k_scan<<<1, 1024, 0, stream>>>(deg, rowstart, cursor);
    k_fill<<<(NE + 255) / 256, 256, 0, stream>>>(src, dst, cursor, adj);
    k_gemm1<<<1250, 256, 0, stream>>>((const float4*)feat, W1, X1b);
    k_agg1<<<(NN * 13 + 255) / 256, 256, 0, stream>>>((const uint4*)X1b, rowstart, deg,
                                                      adj, b1, H1);
    k_gemm2<<<(NN * 20 + 255) / 256, 256, 0, stream>>>(H1, W2, X2);
    k_agg2<<<(NN * 5 + 255) / 256, 256, 0, stream>>>((const float4*)X2, rowstart, deg,
                                                     adj, (const float4*)b2, graph_id,
                                                     g_sum, g_cnt);
    k_final<<<1, 128, 0, stream>>>(g_sum, g_cnt, self_feat, Wf1, bf1, Wf2, bf2,
                                   (float*)d_out);
}

// Round 5
// 592.590 us; speedup vs baseline: 1.3342x; 1.2309x over previous
//
#include <hip/hip_runtime.h>

constexpr int NN = 50000;    // nodes
constexpr int NE = 1600000;  // edges
constexpr int NG = 128;      // graphs

// workspace layout (bytes); all offsets 16B-aligned
#define OFF_DEG      0            // int[50000]
#define OFF_GSUM     200000       // float[128*20]
#define OFF_GCNT     210240       // float[128]
#define ZERO_BYTES   210752
#define OFF_ROWSTART 210752       // int[50000]
#define OFF_CURSOR   410752       // int[50000]
#define OFF_ADJ      610752       // int[1600000]
#define OFF_X1B      7010752      // bf16[50000*128] = feat@W1, row-padded (2 lines)
#define OFF_H1       19810752     // float[50000*100] = relu layer1
#define OFF_X2B      39810752     // bf16[50000*32] = H1@W2, row-padded to 64B (L2-resident 3.2MB)
// end: 43010752 bytes (~43 MB)

// ---- bf16 helpers ---------------------------------------------------------
__device__ __forceinline__ unsigned short f2bf(float x) {      // RNE
    unsigned int v = __float_as_uint(x);
    return (unsigned short)((v + 0x7FFFu + ((v >> 16) & 1u)) >> 16);
}
__device__ __forceinline__ float bflo(unsigned int u) { return __uint_as_float(u << 16); }
__device__ __forceinline__ float bfhi(unsigned int u) { return __uint_as_float(u & 0xFFFF0000u); }

// ---- in-degree histogram -------------------------------------------------
__global__ void k_deg(const int* __restrict__ dst, int* __restrict__ deg) {
    int i = blockIdx.x * blockDim.x + threadIdx.x;
    if (i < NE) atomicAdd(&deg[dst[i]], 1);
}

// ---- exclusive scan of deg -> rowstart (and cursor copy), single block ----
__global__ __launch_bounds__(1024) void k_scan(const int* __restrict__ deg,
                                               int* __restrict__ rowstart,
                                               int* __restrict__ cursor) {
    __shared__ int sums[1024];
    const int t = threadIdx.x;
    const int chunk = (NN + 1023) / 1024;   // 49
    const int lo = t * chunk;
    const int hi = min(lo + chunk, NN);
    int s = 0;
    for (int i = lo; i < hi; ++i) s += deg[i];
    sums[t] = s;
    __syncthreads();
    for (int off = 1; off < 1024; off <<= 1) {
        int v = (t >= off) ? sums[t - off] : 0;
        __syncthreads();
        sums[t] += v;
        __syncthreads();
    }
    int run = (t > 0) ? sums[t - 1] : 0;
    for (int i = lo; i < hi; ++i) {
        rowstart[i] = run;
        cursor[i]   = run;
        run += deg[i];
    }
}

// ---- CSR fill: adj holds src node of every in-edge, grouped by dst --------
__global__ void k_fill(const int* __restrict__ src, const int* __restrict__ dst,
                       int* __restrict__ cursor, int* __restrict__ adj) {
    int i = blockIdx.x * blockDim.x + threadIdx.x;
    if (i < NE) {
        int p = atomicAdd(&cursor[dst[i]], 1);
        adj[p] = src[i];
    }
}

// ---- X1 = bf16(feat @ W1)  (50000x128 @ 128x100), row stride 128 ---------
__global__ __launch_bounds__(256) void k_gemm1(const float4* __restrict__ feat4,
                                               const float* __restrict__ W1,
                                               unsigned short* __restrict__ X1b) {
    const int t = threadIdx.x;
    if (t >= 250) return;
    const int cg = t % 25;            // cols [4cg, 4cg+4)
    const int nq = t / 25;            // node quad within block
    const int node0 = blockIdx.x * 40 + nq * 4;
    const int col0 = cg * 4;

    float acc[4][4];
#pragma unroll
    for (int i = 0; i < 4; ++i)
#pragma unroll
        for (int j = 0; j < 4; ++j) acc[i][j] = 0.f;

    for (int k4 = 0; k4 < 32; ++k4) {
        float4 f[4];
#pragma unroll
        for (int i = 0; i < 4; ++i) f[i] = feat4[(node0 + i) * 32 + k4];
        float4 wr[4];
#pragma unroll
        for (int kk = 0; kk < 4; ++kk)
            wr[kk] = *(const float4*)(W1 + (k4 * 4 + kk) * 100 + col0);
#pragma unroll
        for (int kk = 0; kk < 4; ++kk) {
#pragma unroll
            for (int i = 0; i < 4; ++i) {
                const float fv = (kk == 0) ? f[i].x
                               : (kk == 1) ? f[i].y
                               : (kk == 2) ? f[i].z : f[i].w;
                acc[i][0] += fv * wr[kk].x;
                acc[i][1] += fv * wr[kk].y;
                acc[i][2] += fv * wr[kk].z;
                acc[i][3] += fv * wr[kk].w;
            }
        }
    }
#pragma unroll
    for (int i = 0; i < 4; ++i) {
        ushort4 r;
        r.x = f2bf(acc[i][0]); r.y = f2bf(acc[i][1]);
        r.z = f2bf(acc[i][2]); r.w = f2bf(acc[i][3]);
        *(ushort4*)(X1b + (node0 + i) * 128 + col0) = r;
        if (cg == 24) {  // zero pad cols 100..103 (read by agg1 lane q=12)
            ushort4 z; z.x = z.y = z.z = z.w = 0;
            *(ushort4*)(X1b + (node0 + i) * 128 + 100) = z;
        }
    }
}

// ---- layer-1 aggregate: H1 = relu(where(deg>0, mean(bf16row), bf16row)+b1)
// 13 lanes/node, lane q loads 16B (8 bf16). Edge loop unrolled x4 with
// independent accumulator sets: 4 outstanding gathers/thread (no atomics
// here, so this tests the pure-gather latency-vs-fill-rate question).
__global__ void k_agg1(const uint4* __restrict__ X1u, const int* __restrict__ rowstart,
                       const int* __restrict__ deg, const int* __restrict__ adj,
                       const float* __restrict__ b1, float* __restrict__ H1) {
    int tid = blockIdx.x * blockDim.x + threadIdx.x;
    if (tid >= NN * 13) return;
    const int node = tid / 13;
    const int q = tid - node * 13;        // cols [8q, 8q+8)
    const int rs = rowstart[node];
    const int d = deg[node];
    float a0 = 0.f, a1 = 0.f, a2 = 0.f, a3 = 0.f;
    float a4 = 0.f, a5 = 0.f, a6 = 0.f, a7 = 0.f;
    float c0 = 0.f, c1 = 0.f, c2 = 0.f, c3 = 0.f;
    float c4 = 0.f, c5 = 0.f, c6 = 0.f, c7 = 0.f;
    float e0 = 0.f, e1 = 0.f, e2 = 0.f, e3 = 0.f;
    float e4 = 0.f, e5 = 0.f, e6 = 0.f, e7 = 0.f;
    float g0 = 0.f, g1 = 0.f, g2 = 0.f, g3 = 0.f;
    float g4 = 0.f, g5 = 0.f, g6 = 0.f, g7 = 0.f;
    int i = 0;
    for (; i + 4 <= d; i += 4) {
        const int s0 = adj[rs + i + 0];
        const int s1 = adj[rs + i + 1];
        const int s2 = adj[rs + i + 2];
        const int s3 = adj[rs + i + 3];
        const uint4 u0 = X1u[s0 * 16 + q];
        const uint4 u1 = X1u[s1 * 16 + q];
        const uint4 u2 = X1u[s2 * 16 + q];
        const uint4 u3 = X1u[s3 * 16 + q];
        a0 += bflo(u0.x); a1 += bfhi(u0.x); a2 += bflo(u0.y); a3 += bfhi(u0.y);
        a4 += bflo(u0.z); a5 += bfhi(u0.z); a6 += bflo(u0.w); a7 += bfhi(u0.w);
        c0 += bflo(u1.x); c1 += bfhi(u1.x); c2 += bflo(u1.y); c3 += bfhi(u1.y);
        c4 += bflo(u1.z); c5 += bfhi(u1.z); c6 += bflo(u1.w); c7 += bfhi(u1.w);
        e0 += bflo(u2.x); e1 += bfhi(u2.x); e2 += bflo(u2.y); e3 += bfhi(u2.y);
        e4 += bflo(u2.z); e5 += bfhi(u2.z); e6 += bflo(u2.w); e7 += bfhi(u2.w);
        g0 += bflo(u3.x); g1 += bfhi(u3.x); g2 += bflo(u3.y); g3 += bfhi(u3.y);
        g4 += bflo(u3.z); g5 += bfhi(u3.z); g6 += bflo(u3.w); g7 += bfhi(u3.w);
    }
    for (; i < d; ++i) {
        const int s = adj[rs + i];
        const uint4 u = X1u[s * 16 + q];
        a0 += bflo(u.x); a1 += bfhi(u.x); a2 += bflo(u.y); a3 += bfhi(u.y);
        a4 += bflo(u.z); a5 += bfhi(u.z); a6 += bflo(u.w); a7 += bfhi(u.w);
    }
    a0 = (a0 + c0) + (e0 + g0); a1 = (a1 + c1) + (e1 + g1);
    a2 = (a2 + c2) + (e2 + g2); a3 = (a3 + c3) + (e3 + g3);
    a4 = (a4 + c4) + (e4 + g4); a5 = (a5 + c5) + (e5 + g5);
    a6 = (a6 + c6) + (e6 + g6); a7 = (a7 + c7) + (e7 + g7);
    if (d > 0) {
        const float inv = 1.f / (float)d;
        a0 *= inv; a1 *= inv; a2 *= inv; a3 *= inv;
        a4 *= inv; a5 *= inv; a6 *= inv; a7 *= inv;
    } else {
        const uint4 u = X1u[node * 16 + q];
        a0 = bflo(u.x); a1 = bfhi(u.x); a2 = bflo(u.y); a3 = bfhi(u.y);
        a4 = bflo(u.z); a5 = bfhi(u.z); a6 = bflo(u.w); a7 = bfhi(u.w);
    }
    const int col0 = 8 * q;
    float4 r0;
    r0.x = fmaxf(a0 + b1[col0 + 0], 0.f);
    r0.y = fmaxf(a1 + b1[col0 + 1], 0.f);
    r0.z = fmaxf(a2 + b1[col0 + 2], 0.f);
    r0.w = fmaxf(a3 + b1[col0 + 3], 0.f);
    *(float4*)(H1 + node * 100 + col0) = r0;
    if (q < 12) {                          // cols 100..103 are pad, skip
        float4 r1;
        r1.x = fmaxf(a4 + b1[col0 + 4], 0.f);
        r1.y = fmaxf(a5 + b1[col0 + 5], 0.f);
        r1.z = fmaxf(a6 + b1[col0 + 6], 0.f);
        r1.w = fmaxf(a7 + b1[col0 + 7], 0.f);
        *(float4*)(H1 + node * 100 + col0 + 4) = r1;
    }
}

// ---- X2b = bf16(H1 @ W2)  (50000x100 @ 100x20), row = 32 bf16 (64B) ------
// Thread per (node, col-pair j): cols 2j,2j+1 for j<10; j in [10,16) zero-pad.
__global__ void k_gemm2(const float* __restrict__ H1, const float* __restrict__ W2,
                        unsigned int* __restrict__ X2b) {
    int tid = blockIdx.x * blockDim.x + threadIdx.x;
    if (tid >= NN * 16) return;
    const int node = tid >> 4;
    const int j = tid & 15;
    if (j < 10) {
        const float* h = H1 + node * 100;
        float a0 = 0.f, a1 = 0.f;
#pragma unroll 5
        for (int k = 0; k < 100; ++k) {
            const float hv = h[k];
            a0 += hv * W2[k * 20 + 2 * j];
            a1 += hv * W2[k * 20 + 2 * j + 1];
        }
        X2b[tid] = (unsigned int)f2bf(a0) | ((unsigned int)f2bf(a1) << 16);
    } else {
        X2b[tid] = 0u;
    }
}

// ---- layer-2 aggregate + LDS per-graph reduce -----------------------------
// Block = 320 threads = 64 nodes x 5 lanes. graph_id is SORTED, so a block
// spans 1-2 graphs: accumulate h into LDS[128][20] (LDS atomics), then flush
// only [gmin..gmax] with global atomics (~40 per block vs 4M total before).
__global__ __launch_bounds__(320) void k_agg2(const uint2* __restrict__ X2v,
                                              const int* __restrict__ rowstart,
                                              const int* __restrict__ deg,
                                              const int* __restrict__ adj,
                                              const float* __restrict__ b2,
                                              const int* __restrict__ graph_id,
                                              float* __restrict__ g_sum,
                                              float* __restrict__ g_cnt) {
    __shared__ float lsum[NG * 20];
    __shared__ float lcnt[NG];
    const int t = threadIdx.x;
    for (int i = t; i < NG * 20; i += 320) lsum[i] = 0.f;
    for (int i = t; i < NG; i += 320) lcnt[i] = 0.f;
    __syncthreads();

    const int node = blockIdx.x * 64 + t / 5;
    const int q = t % 5;                      // cols [4q, 4q+4)
    if (node < NN) {
        const int rs = rowstart[node];
        const int d = deg[node];
        float ax = 0.f, ay = 0.f, az = 0.f, aw = 0.f;
        for (int i = 0; i < d; ++i) {
            const int s = adj[rs + i];
            const uint2 u = X2v[s * 8 + q];   // 8B of the 64B bf16 row
            ax += bflo(u.x); ay += bfhi(u.x);
            az += bflo(u.y); aw += bfhi(u.y);
        }
        if (d > 0) {
            const float inv = 1.f / (float)d;
            ax *= inv; ay *= inv; az *= inv; aw *= inv;
        } else {
            const uint2 u = X2v[node * 8 + q];
            ax = bflo(u.x); ay = bfhi(u.x);
            az = bflo(u.y); aw = bfhi(u.y);
        }
        const int col0 = 4 * q;
        const float hx = fmaxf(ax + b2[col0 + 0], 0.f);
        const float hy = fmaxf(ay + b2[col0 + 1], 0.f);
        const float hz = fmaxf(az + b2[col0 + 2], 0.f);
        const float hw = fmaxf(aw + b2[col0 + 3], 0.f);
        const int g = graph_id[node];
        atomicAdd(&lsum[g * 20 + col0 + 0], hx);
        atomicAdd(&lsum[g * 20 + col0 + 1], hy);
        atomicAdd(&lsum[g * 20 + col0 + 2], hz);
        atomicAdd(&lsum[g * 20 + col0 + 3], hw);
        if (q == 0) atomicAdd(&lcnt[g], 1.f);
    }
    __syncthreads();

    const int first = blockIdx.x * 64;
    const int last = min(first + 63, NN - 1);
    const int gmin = graph_id[first];
    const int span = graph_id[last] - gmin + 1;
    for (int idx = t; idx < span * 20; idx += 320) {
        const int g = gmin + idx / 20;
        const int c = idx - (idx / 20) * 20;
        const float v = lsum[g * 20 + c];
        if (v != 0.f) atomicAdd(&g_sum[g * 20 + c], v);
    }
    for (int idx = t; idx < span; idx += 320) {
        const float v = lcnt[gmin + idx];
        if (v != 0.f) atomicAdd(&g_cnt[gmin + idx], v);
    }
}

// ---- final: hg = g_sum/max(cnt,1); out = relu([hg,self]@Wf1+bf1)@Wf2+bf2 --
__global__ __launch_bounds__(128) void k_final(const float* __restrict__ g_sum,
                                               const float* __restrict__ g_cnt,
                                               const float* __restrict__ self_feat,
                                               const float* __restrict__ Wf1,
                                               const float* __restrict__ bf1,
                                               const float* __restrict__ Wf2,
                                               const float* __restrict__ bf2,
                                               float* __restrict__ out) {
    const int g = threadIdx.x;  // 128 graphs, one block
    float fused[36];
    const float cnt = fmaxf(g_cnt[g], 1.f);
    const float inv = 1.f / cnt;
#pragma unroll
    for (int j = 0; j < 20; ++j) fused[j] = g_sum[g * 20 + j] * inv;
#pragma unroll
    for (int j = 0; j < 16; ++j) fused[20 + j] = self_feat[g * 16 + j];
    float o = bf2[0];
#pragma unroll
    for (int i = 0; i < 10; ++i) {
        float t = bf1[i];
#pragma unroll
        for (int k = 0; k < 36; ++k) t += fused[k] * Wf1[k * 10 + i];
        o += fmaxf(t, 0.f) * Wf2[i];
    }
    out[g] = o;
}

extern "C" void kernel_launch(void* const* d_in, const int* in_sizes, int n_in,
                              void* d_out, int out_size, void* d_ws, size_t ws_size,
                              hipStream_t stream) {
    const float* feat      = (const float*)d_in[0];
    const float* self_feat = (const float*)d_in[1];
    const int*   src       = (const int*)d_in[2];
    const int*   dst       = (const int*)d_in[3];
    const int*   graph_id  = (const int*)d_in[4];
    const float* W1        = (const float*)d_in[5];
    const float* b1        = (const float*)d_in[6];
    const float* W2        = (const float*)d_in[7];
    const float* b2        = (const float*)d_in[8];
    const float* Wf1       = (const float*)d_in[9];
    const float* bf1       = (const float*)d_in[10];
    const float* Wf2       = (const float*)d_in[11];
    const float* bf2       = (const float*)d_in[12];

    char* w = (char*)d_ws;
    int*            deg      = (int*)(w + OFF_DEG);
    float*          g_sum    = (float*)(w + OFF_GSUM);
    float*          g_cnt    = (float*)(w + OFF_GCNT);
    int*            rowstart = (int*)(w + OFF_ROWSTART);
    int*            cursor   = (int*)(w + OFF_CURSOR);
    int*            adj      = (int*)(w + OFF_ADJ);
    unsigned short* X1b      = (unsigned short*)(w + OFF_X1B);
    float*          H1       = (float*)(w + OFF_H1);
    unsigned int*   X2b      = (unsigned int*)(w + OFF_X2B);

    hipMemsetAsync(w, 0, ZERO_BYTES, stream);  // deg + g_sum + g_cnt

    k_deg<<<(NE + 255) / 256, 256, 0, stream>>>(dst, deg);
    k_scan<<<1, 1024, 0, stream>>>(deg, rowstart, cursor);
    k_fill<<<(NE + 255) / 256, 256, 0, stream>>>(src, dst, cursor, adj);
    k_gemm1<<<1250, 256, 0, stream>>>((const float4*)feat, W1, X1b);
    k_agg1<<<(NN * 13 + 255) / 256, 256, 0, stream>>>((const uint4*)X1b, rowstart, deg,
                                                      adj, b1, H1);
    k_gemm2<<<(NN * 16 + 255) / 256, 256, 0, stream>>>(H1, W2, X2b);
    k_agg2<<<(NN + 63) / 64, 320, 0, stream>>>((const uint2*)X2b, rowstart, deg,
                                               adj, b2, graph_id, g_sum, g_cnt);
    k_final<<<1, 128, 0, stream>>>(g_sum, g_cnt, self_feat, Wf1, bf1, Wf2, bf2,
                                   (float*)d_out);
}

// Round 6
// 565.021 us; speedup vs baseline: 1.3993x; 1.0488x over previous
//
#include <hip/hip_runtime.h>

constexpr int NN = 50000;    // nodes
constexpr int NE = 1600000;  // edges
constexpr int NG = 128;      // graphs

// k_fill pass structure: 8 passes over disjoint dst ranges of 6250 nodes.
constexpr int FILL_PASSES = 8;
constexpr int NODES_PER_PASS = 6250;              // 8*6250 = 50000
constexpr int BLOCKS_PER_PASS = (NE + 255) / 256; // 6250

// workspace layout (bytes); all offsets 16B-aligned
#define OFF_DEG      0            // int[50000]
#define OFF_GSUM     200000       // float[128*20]
#define OFF_GCNT     210240       // float[128]
#define ZERO_BYTES   210752
#define OFF_ROWSTART 210752       // int[50000]
#define OFF_CURSOR   410752       // int[50000]
#define OFF_ADJ      610752       // ushort[1600000] (3.2MB; region oversized)
#define OFF_X1B      7010752      // bf16[50000*128] = feat@W1, row-padded (2 lines)
#define OFF_H1       19810752     // float[50000*100] = relu layer1
#define OFF_X2B      39810752     // bf16[50000*32] = H1@W2, row-padded to 64B
// end: 43010752 bytes (~43 MB)

// ---- bf16 helpers ---------------------------------------------------------
__device__ __forceinline__ unsigned short f2bf(float x) {      // RNE
    unsigned int v = __float_as_uint(x);
    return (unsigned short)((v + 0x7FFFu + ((v >> 16) & 1u)) >> 16);
}
__device__ __forceinline__ float bflo(unsigned int u) { return __uint_as_float(u << 16); }
__device__ __forceinline__ float bfhi(unsigned int u) { return __uint_as_float(u & 0xFFFF0000u); }

// ---- in-degree histogram -------------------------------------------------
__global__ void k_deg(const int* __restrict__ dst, int* __restrict__ deg) {
    int i = blockIdx.x * blockDim.x + threadIdx.x;
    if (i < NE) atomicAdd(&deg[dst[i]], 1);
}

// ---- exclusive scan of deg -> rowstart (and cursor copy), single block ----
__global__ __launch_bounds__(1024) void k_scan(const int* __restrict__ deg,
                                               int* __restrict__ rowstart,
                                               int* __restrict__ cursor) {
    __shared__ int sums[1024];
    const int t = threadIdx.x;
    const int chunk = (NN + 1023) / 1024;   // 49
    const int lo = t * chunk;
    const int hi = min(lo + chunk, NN);
    int s = 0;
    for (int i = lo; i < hi; ++i) s += deg[i];
    sums[t] = s;
    __syncthreads();
    for (int off = 1; off < 1024; off <<= 1) {
        int v = (t >= off) ? sums[t - off] : 0;
        __syncthreads();
        sums[t] += v;
        __syncthreads();
    }
    int run = (t > 0) ? sums[t - 1] : 0;
    for (int i = lo; i < hi; ++i) {
        rowstart[i] = run;
        cursor[i]   = run;
        run += deg[i];
    }
}

// ---- CSR fill, dst-range passes -------------------------------------------
// pass = blockIdx/6250 handles dst in [pass*6250, (pass+1)*6250). Each pass's
// adj region (~0.4MB) is fully written while temporally clustered -> full-line
// writebacks instead of 64B fragments. Correct under ANY block order (ranges
// disjoint, cursors global atomics).
__global__ void k_fill(const int* __restrict__ src, const int* __restrict__ dst,
                       int* __restrict__ cursor, unsigned short* __restrict__ adj) {
    const int pass = blockIdx.x / BLOCKS_PER_PASS;
    const int chunk = blockIdx.x - pass * BLOCKS_PER_PASS;
    const int i = chunk * 256 + threadIdx.x;
    if (i >= NE) return;
    const int d = dst[i];
    const int lo = pass * NODES_PER_PASS;
    if (d >= lo && d < lo + NODES_PER_PASS) {
        const int p = atomicAdd(&cursor[d], 1);
        adj[p] = (unsigned short)src[i];
    }
}

// ---- X1 = bf16(feat @ W1)  (50000x128 @ 128x100), row stride 128 ---------
__global__ __launch_bounds__(256) void k_gemm1(const float4* __restrict__ feat4,
                                               const float* __restrict__ W1,
                                               unsigned short* __restrict__ X1b) {
    const int t = threadIdx.x;
    if (t >= 250) return;
    const int cg = t % 25;            // cols [4cg, 4cg+4)
    const int nq = t / 25;            // node quad within block
    const int node0 = blockIdx.x * 40 + nq * 4;
    const int col0 = cg * 4;

    float acc[4][4];
#pragma unroll
    for (int i = 0; i < 4; ++i)
#pragma unroll
        for (int j = 0; j < 4; ++j) acc[i][j] = 0.f;

    for (int k4 = 0; k4 < 32; ++k4) {
        float4 f[4];
#pragma unroll
        for (int i = 0; i < 4; ++i) f[i] = feat4[(node0 + i) * 32 + k4];
        float4 wr[4];
#pragma unroll
        for (int kk = 0; kk < 4; ++kk)
            wr[kk] = *(const float4*)(W1 + (k4 * 4 + kk) * 100 + col0);
#pragma unroll
        for (int kk = 0; kk < 4; ++kk) {
#pragma unroll
            for (int i = 0; i < 4; ++i) {
                const float fv = (kk == 0) ? f[i].x
                               : (kk == 1) ? f[i].y
                               : (kk == 2) ? f[i].z : f[i].w;
                acc[i][0] += fv * wr[kk].x;
                acc[i][1] += fv * wr[kk].y;
                acc[i][2] += fv * wr[kk].z;
                acc[i][3] += fv * wr[kk].w;
            }
        }
    }
#pragma unroll
    for (int i = 0; i < 4; ++i) {
        ushort4 r;
        r.x = f2bf(acc[i][0]); r.y = f2bf(acc[i][1]);
        r.z = f2bf(acc[i][2]); r.w = f2bf(acc[i][3]);
        *(ushort4*)(X1b + (node0 + i) * 128 + col0) = r;
        if (cg == 24) {  // zero pad cols 100..103 (read by agg1 lane q=12)
            ushort4 z; z.x = z.y = z.z = z.w = 0;
            *(ushort4*)(X1b + (node0 + i) * 128 + 100) = z;
        }
    }
}

// ---- layer-1 aggregate: H1 = relu(where(deg>0, mean(bf16row), bf16row)+b1)
// 13 lanes/node, lane q loads 16B (8 bf16). Serial edge loop (R3/R5: unroll
// regresses this gather structure).
__global__ void k_agg1(const uint4* __restrict__ X1u, const int* __restrict__ rowstart,
                       const int* __restrict__ deg, const unsigned short* __restrict__ adj,
                       const float* __restrict__ b1, float* __restrict__ H1) {
    int tid = blockIdx.x * blockDim.x + threadIdx.x;
    if (tid >= NN * 13) return;
    const int node = tid / 13;
    const int q = tid - node * 13;        // cols [8q, 8q+8)
    const int rs = rowstart[node];
    const int d = deg[node];
    float a0 = 0.f, a1 = 0.f, a2 = 0.f, a3 = 0.f;
    float a4 = 0.f, a5 = 0.f, a6 = 0.f, a7 = 0.f;
    for (int i = 0; i < d; ++i) {
        const int s = (int)adj[rs + i];     // broadcast across the 13-lane group
        const uint4 u = X1u[s * 16 + q];    // 16B of the 256B row
        a0 += bflo(u.x); a1 += bfhi(u.x);
        a2 += bflo(u.y); a3 += bfhi(u.y);
        a4 += bflo(u.z); a5 += bfhi(u.z);
        a6 += bflo(u.w); a7 += bfhi(u.w);
    }
    if (d > 0) {
        const float inv = 1.f / (float)d;
        a0 *= inv; a1 *= inv; a2 *= inv; a3 *= inv;
        a4 *= inv; a5 *= inv; a6 *= inv; a7 *= inv;
    } else {
        const uint4 u = X1u[node * 16 + q];
        a0 = bflo(u.x); a1 = bfhi(u.x);
        a2 = bflo(u.y); a3 = bfhi(u.y);
        a4 = bflo(u.z); a5 = bfhi(u.z);
        a6 = bflo(u.w); a7 = bfhi(u.w);
    }
    const int col0 = 8 * q;
    float4 r0;
    r0.x = fmaxf(a0 + b1[col0 + 0], 0.f);
    r0.y = fmaxf(a1 + b1[col0 + 1], 0.f);
    r0.z = fmaxf(a2 + b1[col0 + 2], 0.f);
    r0.w = fmaxf(a3 + b1[col0 + 3], 0.f);
    *(float4*)(H1 + node * 100 + col0) = r0;
    if (q < 12) {                          // cols 100..103 are pad, skip
        float4 r1;
        r1.x = fmaxf(a4 + b1[col0 + 4], 0.f);
        r1.y = fmaxf(a5 + b1[col0 + 5], 0.f);
        r1.z = fmaxf(a6 + b1[col0 + 6], 0.f);
        r1.w = fmaxf(a7 + b1[col0 + 7], 0.f);
        *(float4*)(H1 + node * 100 + col0 + 4) = r1;
    }
}

// ---- X2b = bf16(H1 @ W2)  (50000x100 @ 100x20), row = 32 bf16 (64B) ------
__global__ void k_gemm2(const float* __restrict__ H1, const float* __restrict__ W2,
                        unsigned int* __restrict__ X2b) {
    int tid = blockIdx.x * blockDim.x + threadIdx.x;
    if (tid >= NN * 16) return;
    const int node = tid >> 4;
    const int j = tid & 15;
    if (j < 10) {
        const float* h = H1 + node * 100;
        float a0 = 0.f, a1 = 0.f;
#pragma unroll 5
        for (int k = 0; k < 100; ++k) {
            const float hv = h[k];
            a0 += hv * W2[k * 20 + 2 * j];
            a1 += hv * W2[k * 20 + 2 * j + 1];
        }
        X2b[tid] = (unsigned int)f2bf(a0) | ((unsigned int)f2bf(a1) << 16);
    } else {
        X2b[tid] = 0u;
    }
}

// ---- layer-2 aggregate + LDS per-graph reduce -----------------------------
__global__ __launch_bounds__(320) void k_agg2(const uint2* __restrict__ X2v,
                                              const int* __restrict__ rowstart,
                                              const int* __restrict__ deg,
                                              const unsigned short* __restrict__ adj,
                                              const float* __restrict__ b2,
                                              const int* __restrict__ graph_id,
                                              float* __restrict__ g_sum,
                                              float* __restrict__ g_cnt) {
    __shared__ float lsum[NG * 20];
    __shared__ float lcnt[NG];
    const int t = threadIdx.x;
    for (int i = t; i < NG * 20; i += 320) lsum[i] = 0.f;
    for (int i = t; i < NG; i += 320) lcnt[i] = 0.f;
    __syncthreads();

    const int node = blockIdx.x * 64 + t / 5;
    const int q = t % 5;                      // cols [4q, 4q+4)
    if (node < NN) {
        const int rs = rowstart[node];
        const int d = deg[node];
        float ax = 0.f, ay = 0.f, az = 0.f, aw = 0.f;
        for (int i = 0; i < d; ++i) {
            const int s = (int)adj[rs + i];
            const uint2 u = X2v[s * 8 + q];   // 8B of the 64B bf16 row
            ax += bflo(u.x); ay += bfhi(u.x);
            az += bflo(u.y); aw += bfhi(u.y);
        }
        if (d > 0) {
            const float inv = 1.f / (float)d;
            ax *= inv; ay *= inv; az *= inv; aw *= inv;
        } else {
            const uint2 u = X2v[node * 8 + q];
            ax = bflo(u.x); ay = bfhi(u.x);
            az = bflo(u.y); aw = bfhi(u.y);
        }
        const int col0 = 4 * q;
        const float hx = fmaxf(ax + b2[col0 + 0], 0.f);
        const float hy = fmaxf(ay + b2[col0 + 1], 0.f);
        const float hz = fmaxf(az + b2[col0 + 2], 0.f);
        const float hw = fmaxf(aw + b2[col0 + 3], 0.f);
        const int g = graph_id[node];
        atomicAdd(&lsum[g * 20 + col0 + 0], hx);
        atomicAdd(&lsum[g * 20 + col0 + 1], hy);
        atomicAdd(&lsum[g * 20 + col0 + 2], hz);
        atomicAdd(&lsum[g * 20 + col0 + 3], hw);
        if (q == 0) atomicAdd(&lcnt[g], 1.f);
    }
    __syncthreads();

    const int first = blockIdx.x * 64;
    const int last = min(first + 63, NN - 1);
    const int gmin = graph_id[first];
    const int span = graph_id[last] - gmin + 1;
    for (int idx = t; idx < span * 20; idx += 320) {
        const int g = gmin + idx / 20;
        const int c = idx - (idx / 20) * 20;
        const float v = lsum[g * 20 + c];
        if (v != 0.f) atomicAdd(&g_sum[g * 20 + c], v);
    }
    for (int idx = t; idx < span; idx += 320) {
        const float v = lcnt[gmin + idx];
        if (v != 0.f) atomicAdd(&g_cnt[gmin + idx], v);
    }
}

// ---- final: hg = g_sum/max(cnt,1); out = relu([hg,self]@Wf1+bf1)@Wf2+bf2 --
__global__ __launch_bounds__(128) void k_final(const float* __restrict__ g_sum,
                                               const float* __restrict__ g_cnt,
                                               const float* __restrict__ self_feat,
                                               const float* __restrict__ Wf1,
                                               const float* __restrict__ bf1,
                                               const float* __restrict__ Wf2,
                                               const float* __restrict__ bf2,
                                               float* __restrict__ out) {
    const int g = threadIdx.x;  // 128 graphs, one block
    float fused[36];
    const float cnt = fmaxf(g_cnt[g], 1.f);
    const float inv = 1.f / cnt;
#pragma unroll
    for (int j = 0; j < 20; ++j) fused[j] = g_sum[g * 20 + j] * inv;
#pragma unroll
    for (int j = 0; j < 16; ++j) fused[20 + j] = self_feat[g * 16 + j];
    float o = bf2[0];
#pragma unroll
    for (int i = 0; i < 10; ++i) {
        float t = bf1[i];
#pragma unroll
        for (int k = 0; k < 36; ++k) t += fused[k] * Wf1[k * 10 + i];
        o += fmaxf(t, 0.f) * Wf2[i];
    }
    out[g] = o;
}

extern "C" void kernel_launch(void* const* d_in, const int* in_sizes, int n_in,
                              void* d_out, int out_size, void* d_ws, size_t ws_size,
                              hipStream_t stream) {
    const float* feat      = (const float*)d_in[0];
    const float* self_feat = (const float*)d_in[1];
    const int*   src       = (const int*)d_in[2];
    const int*   dst       = (const int*)d_in[3];
    const int*   graph_id  = (const int*)d_in[4];
    const float* W1        = (const float*)d_in[5];
    const float* b1        = (const float*)d_in[6];
    const float* W2        = (const float*)d_in[7];
    const float* b2        = (const float*)d_in[8];
    const float* Wf1       = (const float*)d_in[9];
    const float* bf1       = (const float*)d_in[10];
    const float* Wf2       = (const float*)d_in[11];
    const float* bf2       = (const float*)d_in[12];

    char* w = (char*)d_ws;
    int*            deg      = (int*)(w + OFF_DEG);
    float*          g_sum    = (float*)(w + OFF_GSUM);
    float*          g_cnt    = (float*)(w + OFF_GCNT);
    int*            rowstart = (int*)(w + OFF_ROWSTART);
    int*            cursor   = (int*)(w + OFF_CURSOR);
    unsigned short* adj      = (unsigned short*)(w + OFF_ADJ);
    unsigned short* X1b      = (unsigned short*)(w + OFF_X1B);
    float*          H1       = (float*)(w + OFF_H1);
    unsigned int*   X2b      = (unsigned int*)(w + OFF_X2B);

    hipMemsetAsync(w, 0, ZERO_BYTES, stream);  // deg + g_sum + g_cnt

    k_deg<<<(NE + 255) / 256, 256, 0, stream>>>(dst, deg);
    k_scan<<<1, 1024, 0, stream>>>(deg, rowstart, cursor);
    k_fill<<<FILL_PASSES * BLOCKS_PER_PASS, 256, 0, stream>>>(src, dst, cursor, adj);
    k_gemm1<<<1250, 256, 0, stream>>>((const float4*)feat, W1, X1b);
    k_agg1<<<(NN * 13 + 255) / 256, 256, 0, stream>>>((const uint4*)X1b, rowstart, deg,
                                                      adj, b1, H1);
    k_gemm2<<<(NN * 16 + 255) / 256, 256, 0, stream>>>(H1, W2, X2b);
    k_agg2<<<(NN + 63) / 64, 320, 0, stream>>>((const uint2*)X2b, rowstart, deg,
                                               adj, b2, graph_id, g_sum, g_cnt);
    k_final<<<1, 128, 0, stream>>>(g_sum, g_cnt, self_feat, Wf1, bf1, Wf2, bf2,
                                   (float*)d_out);
}

// Round 7
// 463.400 us; speedup vs baseline: 1.7062x; 1.2193x over previous
//
#include <hip/hip_runtime.h>

constexpr int NN = 50000;    // nodes
constexpr int NE = 1600000;  // edges
constexpr int NG = 128;      // graphs

// k_fill pass structure: 8 passes over disjoint dst ranges of 6250 nodes.
constexpr int FILL_PASSES = 8;
constexpr int NODES_PER_PASS = 6250;              // 8*6250 = 50000
constexpr int BLOCKS_PER_PASS = (NE + 255) / 256; // 6250

constexpr int SCAN_BLOCKS = (NN + 255) / 256;     // 196

// workspace layout (bytes); all offsets 16B-aligned
#define OFF_DEG      0            // int[50000]
#define OFF_GSUM     200000       // float[128*20]
#define OFF_GCNT     210240       // float[128]
#define ZERO_BYTES   210752
#define OFF_ROWSTART 210752       // int[50000]
#define OFF_CURSOR   410752       // int[50000]
#define OFF_ADJ      610752       // ushort[1600000] (3.2MB)
#define OFF_BSUM     3810752      // int[196] scan block sums
#define OFF_BOFF     3811552      // int[196] scan block offsets
#define OFF_X1B      7010752      // bf16[50000*128] = feat@W1, row-padded (2 lines)
#define OFF_H1       19810752     // float[50000*100] = relu layer1
#define OFF_X2B      39810752     // bf16[50000*32] = H1@W2, row-padded to 64B
// end: 43010752 bytes (~43 MB)

// ---- bf16 helpers ---------------------------------------------------------
__device__ __forceinline__ unsigned short f2bf(float x) {      // RNE
    unsigned int v = __float_as_uint(x);
    return (unsigned short)((v + 0x7FFFu + ((v >> 16) & 1u)) >> 16);
}
__device__ __forceinline__ float bflo(unsigned int u) { return __uint_as_float(u << 16); }
__device__ __forceinline__ float bfhi(unsigned int u) { return __uint_as_float(u & 0xFFFF0000u); }

// ---- in-degree histogram -------------------------------------------------
__global__ void k_deg(const int* __restrict__ dst, int* __restrict__ deg) {
    int i = blockIdx.x * blockDim.x + threadIdx.x;
    if (i < NE) atomicAdd(&deg[dst[i]], 1);
}

// ---- scan phase A: per-block reduce of deg --------------------------------
__global__ __launch_bounds__(256) void k_scanA(const int* __restrict__ deg,
                                               int* __restrict__ bsum) {
    __shared__ int sr[256];
    const int t = threadIdx.x;
    const int i = blockIdx.x * 256 + t;
    sr[t] = (i < NN) ? deg[i] : 0;
    __syncthreads();
    for (int off = 128; off > 0; off >>= 1) {
        if (t < off) sr[t] += sr[t + off];
        __syncthreads();
    }
    if (t == 0) bsum[blockIdx.x] = sr[0];
}

// ---- scan phase B: exclusive scan of 196 block sums (1 block) -------------
__global__ __launch_bounds__(256) void k_scanB(const int* __restrict__ bsum,
                                               int* __restrict__ boff) {
    __shared__ int sc[256];
    const int t = threadIdx.x;
    const int val = (t < SCAN_BLOCKS) ? bsum[t] : 0;
    sc[t] = val;
    __syncthreads();
    for (int off = 1; off < 256; off <<= 1) {
        const int v = (t >= off) ? sc[t - off] : 0;
        __syncthreads();
        sc[t] += v;
        __syncthreads();
    }
    if (t < SCAN_BLOCKS) boff[t] = sc[t] - val;   // exclusive
}

// ---- scan phase C: per-block exclusive scan + offset -> rowstart, cursor --
__global__ __launch_bounds__(256) void k_scanC(const int* __restrict__ deg,
                                               const int* __restrict__ boff,
                                               int* __restrict__ rowstart,
                                               int* __restrict__ cursor) {
    __shared__ int sc[256];
    const int t = threadIdx.x;
    const int i = blockIdx.x * 256 + t;
    const int val = (i < NN) ? deg[i] : 0;
    sc[t] = val;
    __syncthreads();
    for (int off = 1; off < 256; off <<= 1) {
        const int v = (t >= off) ? sc[t - off] : 0;
        __syncthreads();
        sc[t] += v;
        __syncthreads();
    }
    if (i < NN) {
        const int r = boff[blockIdx.x] + sc[t] - val;
        rowstart[i] = r;
        cursor[i]   = r;
    }
}

// ---- CSR fill, dst-range passes -------------------------------------------
// pass = blockIdx/6250 handles dst in [pass*6250, (pass+1)*6250). Each pass's
// adj region (~0.4MB) is fully written while temporally clustered -> full-line
// writebacks instead of 64B fragments. Correct under ANY block order.
__global__ void k_fill(const int* __restrict__ src, const int* __restrict__ dst,
                       int* __restrict__ cursor, unsigned short* __restrict__ adj) {
    const int pass = blockIdx.x / BLOCKS_PER_PASS;
    const int chunk = blockIdx.x - pass * BLOCKS_PER_PASS;
    const int i = chunk * 256 + threadIdx.x;
    if (i >= NE) return;
    const int d = dst[i];
    const int lo = pass * NODES_PER_PASS;
    if (d >= lo && d < lo + NODES_PER_PASS) {
        const int p = atomicAdd(&cursor[d], 1);
        adj[p] = (unsigned short)src[i];
    }
}

// ---- X1 = bf16(feat @ W1)  (50000x128 @ 128x100), row stride 128 ---------
__global__ __launch_bounds__(256) void k_gemm1(const float4* __restrict__ feat4,
                                               const float* __restrict__ W1,
                                               unsigned short* __restrict__ X1b) {
    const int t = threadIdx.x;
    if (t >= 250) return;
    const int cg = t % 25;            // cols [4cg, 4cg+4)
    const int nq = t / 25;            // node quad within block
    const int node0 = blockIdx.x * 40 + nq * 4;
    const int col0 = cg * 4;

    float acc[4][4];
#pragma unroll
    for (int i = 0; i < 4; ++i)
#pragma unroll
        for (int j = 0; j < 4; ++j) acc[i][j] = 0.f;

    for (int k4 = 0; k4 < 32; ++k4) {
        float4 f[4];
#pragma unroll
        for (int i = 0; i < 4; ++i) f[i] = feat4[(node0 + i) * 32 + k4];
        float4 wr[4];
#pragma unroll
        for (int kk = 0; kk < 4; ++kk)
            wr[kk] = *(const float4*)(W1 + (k4 * 4 + kk) * 100 + col0);
#pragma unroll
        for (int kk = 0; kk < 4; ++kk) {
#pragma unroll
            for (int i = 0; i < 4; ++i) {
                const float fv = (kk == 0) ? f[i].x
                               : (kk == 1) ? f[i].y
                               : (kk == 2) ? f[i].z : f[i].w;
                acc[i][0] += fv * wr[kk].x;
                acc[i][1] += fv * wr[kk].y;
                acc[i][2] += fv * wr[kk].z;
                acc[i][3] += fv * wr[kk].w;
            }
        }
    }
#pragma unroll
    for (int i = 0; i < 4; ++i) {
        ushort4 r;
        r.x = f2bf(acc[i][0]); r.y = f2bf(acc[i][1]);
        r.z = f2bf(acc[i][2]); r.w = f2bf(acc[i][3]);
        *(ushort4*)(X1b + (node0 + i) * 128 + col0) = r;
        if (cg == 24) {  // zero pad cols 100..103 (read by agg1 lane q=12)
            ushort4 z; z.x = z.y = z.z = z.w = 0;
            *(ushort4*)(X1b + (node0 + i) * 128 + 100) = z;
        }
    }
}

// ---- layer-1 aggregate: H1 = relu(where(deg>0, mean(bf16row), bf16row)+b1)
// 13 lanes/node, lane q loads 16B (8 bf16). Serial edge loop (R3/R5: unroll
// regresses this gather structure).
__global__ void k_agg1(const uint4* __restrict__ X1u, const int* __restrict__ rowstart,
                       const int* __restrict__ deg, const unsigned short* __restrict__ adj,
                       const float* __restrict__ b1, float* __restrict__ H1) {
    int tid = blockIdx.x * blockDim.x + threadIdx.x;
    if (tid >= NN * 13) return;
    const int node = tid / 13;
    const int q = tid - node * 13;        // cols [8q, 8q+8)
    const int rs = rowstart[node];
    const int d = deg[node];
    float a0 = 0.f, a1 = 0.f, a2 = 0.f, a3 = 0.f;
    float a4 = 0.f, a5 = 0.f, a6 = 0.f, a7 = 0.f;
    for (int i = 0; i < d; ++i) {
        const int s = (int)adj[rs + i];     // broadcast across the 13-lane group
        const uint4 u = X1u[s * 16 + q];    // 16B of the 256B row
        a0 += bflo(u.x); a1 += bfhi(u.x);
        a2 += bflo(u.y); a3 += bfhi(u.y);
        a4 += bflo(u.z); a5 += bfhi(u.z);
        a6 += bflo(u.w); a7 += bfhi(u.w);
    }
    if (d > 0) {
        const float inv = 1.f / (float)d;
        a0 *= inv; a1 *= inv; a2 *= inv; a3 *= inv;
        a4 *= inv; a5 *= inv; a6 *= inv; a7 *= inv;
    } else {
        const uint4 u = X1u[node * 16 + q];
        a0 = bflo(u.x); a1 = bfhi(u.x);
        a2 = bflo(u.y); a3 = bfhi(u.y);
        a4 = bflo(u.z); a5 = bfhi(u.z);
        a6 = bflo(u.w); a7 = bfhi(u.w);
    }
    const int col0 = 8 * q;
    float4 r0;
    r0.x = fmaxf(a0 + b1[col0 + 0], 0.f);
    r0.y = fmaxf(a1 + b1[col0 + 1], 0.f);
    r0.z = fmaxf(a2 + b1[col0 + 2], 0.f);
    r0.w = fmaxf(a3 + b1[col0 + 3], 0.f);
    *(float4*)(H1 + node * 100 + col0) = r0;
    if (q < 12) {                          // cols 100..103 are pad, skip
        float4 r1;
        r1.x = fmaxf(a4 + b1[col0 + 4], 0.f);
        r1.y = fmaxf(a5 + b1[col0 + 5], 0.f);
        r1.z = fmaxf(a6 + b1[col0 + 6], 0.f);
        r1.w = fmaxf(a7 + b1[col0 + 7], 0.f);
        *(float4*)(H1 + node * 100 + col0 + 4) = r1;
    }
}

// ---- X2b = bf16(H1 @ W2)  (50000x100 @ 100x20), row = 32 bf16 (64B) ------
__global__ void k_gemm2(const float* __restrict__ H1, const float* __restrict__ W2,
                        unsigned int* __restrict__ X2b) {
    int tid = blockIdx.x * blockDim.x + threadIdx.x;
    if (tid >= NN * 16) return;
    const int node = tid >> 4;
    const int j = tid & 15;
    if (j < 10) {
        const float* h = H1 + node * 100;
        float a0 = 0.f, a1 = 0.f;
#pragma unroll 5
        for (int k = 0; k < 100; ++k) {
            const float hv = h[k];
            a0 += hv * W2[k * 20 + 2 * j];
            a1 += hv * W2[k * 20 + 2 * j + 1];
        }
        X2b[tid] = (unsigned int)f2bf(a0) | ((unsigned int)f2bf(a1) << 16);
    } else {
        X2b[tid] = 0u;
    }
}

// ---- layer-2 aggregate + LDS per-graph reduce -----------------------------
__global__ __launch_bounds__(320) void k_agg2(const uint2* __restrict__ X2v,
                                              const int* __restrict__ rowstart,
                                              const int* __restrict__ deg,
                                              const unsigned short* __restrict__ adj,
                                              const float* __restrict__ b2,
                                              const int* __restrict__ graph_id,
                                              float* __restrict__ g_sum,
                                              float* __restrict__ g_cnt) {
    __shared__ float lsum[NG * 20];
    __shared__ float lcnt[NG];
    const int t = threadIdx.x;
    for (int i = t; i < NG * 20; i += 320) lsum[i] = 0.f;
    for (int i = t; i < NG; i += 320) lcnt[i] = 0.f;
    __syncthreads();

    const int node = blockIdx.x * 64 + t / 5;
    const int q = t % 5;                      // cols [4q, 4q+4)
    if (node < NN) {
        const int rs = rowstart[node];
        const int d = deg[node];
        float ax = 0.f, ay = 0.f, az = 0.f, aw = 0.f;
        for (int i = 0; i < d; ++i) {
            const int s = (int)adj[rs + i];
            const uint2 u = X2v[s * 8 + q];   // 8B of the 64B bf16 row
            ax += bflo(u.x); ay += bfhi(u.x);
            az += bflo(u.y); aw += bfhi(u.y);
        }
        if (d > 0) {
            const float inv = 1.f / (float)d;
            ax *= inv; ay *= inv; az *= inv; aw *= inv;
        } else {
            const uint2 u = X2v[node * 8 + q];
            ax = bflo(u.x); ay = bfhi(u.x);
            az = bflo(u.y); aw = bfhi(u.y);
        }
        const int col0 = 4 * q;
        const float hx = fmaxf(ax + b2[col0 + 0], 0.f);
        const float hy = fmaxf(ay + b2[col0 + 1], 0.f);
        const float hz = fmaxf(az + b2[col0 + 2], 0.f);
        const float hw = fmaxf(aw + b2[col0 + 3], 0.f);
        const int g = graph_id[node];
        atomicAdd(&lsum[g * 20 + col0 + 0], hx);
        atomicAdd(&lsum[g * 20 + col0 + 1], hy);
        atomicAdd(&lsum[g * 20 + col0 + 2], hz);
        atomicAdd(&lsum[g * 20 + col0 + 3], hw);
        if (q == 0) atomicAdd(&lcnt[g], 1.f);
    }
    __syncthreads();

    const int first = blockIdx.x * 64;
    const int last = min(first + 63, NN - 1);
    const int gmin = graph_id[first];
    const int span = graph_id[last] - gmin + 1;
    for (int idx = t; idx < span * 20; idx += 320) {
        const int g = gmin + idx / 20;
        const int c = idx - (idx / 20) * 20;
        const float v = lsum[g * 20 + c];
        if (v != 0.f) atomicAdd(&g_sum[g * 20 + c], v);
    }
    for (int idx = t; idx < span; idx += 320) {
        const float v = lcnt[gmin + idx];
        if (v != 0.f) atomicAdd(&g_cnt[gmin + idx], v);
    }
}

// ---- final: hg = g_sum/max(cnt,1); out = relu([hg,self]@Wf1+bf1)@Wf2+bf2 --
__global__ __launch_bounds__(128) void k_final(const float* __restrict__ g_sum,
                                               const float* __restrict__ g_cnt,
                                               const float* __restrict__ self_feat,
                                               const float* __restrict__ Wf1,
                                               const float* __restrict__ bf1,
                                               const float* __restrict__ Wf2,
                                               const float* __restrict__ bf2,
                                               float* __restrict__ out) {
    const int g = threadIdx.x;  // 128 graphs, one block
    float fused[36];
    const float cnt = fmaxf(g_cnt[g], 1.f);
    const float inv = 1.f / cnt;
#pragma unroll
    for (int j = 0; j < 20; ++j) fused[j] = g_sum[g * 20 + j] * inv;
#pragma unroll
    for (int j = 0; j < 16; ++j) fused[20 + j] = self_feat[g * 16 + j];
    float o = bf2[0];
#pragma unroll
    for (int i = 0; i < 10; ++i) {
        float t = bf1[i];
#pragma unroll
        for (int k = 0; k < 36; ++k) t += fused[k] * Wf1[k * 10 + i];
        o += fmaxf(t, 0.f) * Wf2[i];
    }
    out[g] = o;
}

extern "C" void kernel_launch(void* const* d_in, const int* in_sizes, int n_in,
                              void* d_out, int out_size, void* d_ws, size_t ws_size,
                              hipStream_t stream) {
    const float* feat      = (const float*)d_in[0];
    const float* self_feat = (const float*)d_in[1];
    const int*   src       = (const int*)d_in[2];
    const int*   dst       = (const int*)d_in[3];
    const int*   graph_id  = (const int*)d_in[4];
    const float* W1        = (const float*)d_in[5];
    const float* b1        = (const float*)d_in[6];
    const float* W2        = (const float*)d_in[7];
    const float* b2        = (const float*)d_in[8];
    const float* Wf1       = (const float*)d_in[9];
    const float* bf1       = (const float*)d_in[10];
    const float* Wf2       = (const float*)d_in[11];
    const float* bf2       = (const float*)d_in[12];

    char* w = (char*)d_ws;
    int*            deg      = (int*)(w + OFF_DEG);
    float*          g_sum    = (float*)(w + OFF_GSUM);
    float*          g_cnt    = (float*)(w + OFF_GCNT);
    int*            rowstart = (int*)(w + OFF_ROWSTART);
    int*            cursor   = (int*)(w + OFF_CURSOR);
    unsigned short* adj      = (unsigned short*)(w + OFF_ADJ);
    int*            bsum     = (int*)(w + OFF_BSUM);
    int*            boff     = (int*)(w + OFF_BOFF);
    unsigned short* X1b      = (unsigned short*)(w + OFF_X1B);
    float*          H1       = (float*)(w + OFF_H1);
    unsigned int*   X2b      = (unsigned int*)(w + OFF_X2B);

    hipMemsetAsync(w, 0, ZERO_BYTES, stream);  // deg + g_sum + g_cnt

    k_deg<<<(NE + 255) / 256, 256, 0, stream>>>(dst, deg);
    k_scanA<<<SCAN_BLOCKS, 256, 0, stream>>>(deg, bsum);
    k_scanB<<<1, 256, 0, stream>>>(bsum, boff);
    k_scanC<<<SCAN_BLOCKS, 256, 0, stream>>>(deg, boff, rowstart, cursor);
    k_fill<<<FILL_PASSES * BLOCKS_PER_PASS, 256, 0, stream>>>(src, dst, cursor, adj);
    k_gemm1<<<1250, 256, 0, stream>>>((const float4*)feat, W1, X1b);
    k_agg1<<<(NN * 13 + 255) / 256, 256, 0, stream>>>((const uint4*)X1b, rowstart, deg,
                                                      adj, b1, H1);
    k_gemm2<<<(NN * 16 + 255) / 256, 256, 0, stream>>>(H1, W2, X2b);
    k_agg2<<<(NN + 63) / 64, 320, 0, stream>>>((const uint2*)X2b, rowstart, deg,
                                               adj, b2, graph_id, g_sum, g_cnt);
    k_final<<<1, 128, 0, stream>>>(g_sum, g_cnt, self_feat, Wf1, bf1, Wf2, bf2,
                                   (float*)d_out);
}

// Round 8
// 379.363 us; speedup vs baseline: 2.0842x; 1.2215x over previous
//
#include <hip/hip_runtime.h>

constexpr int NN = 50000;    // nodes
constexpr int NE = 1600000;  // edges
constexpr int NG = 128;      // graphs
constexpr int BSTRIDE = 96;  // adj bucket slots per node (deg~Poisson(32), max~58)

// workspace layout (bytes)
#define OFF_CNT      0            // int[50000] atomic cursor; == deg after fill
#define OFF_GSUM     200000       // float[128*20]
#define OFF_GCNT     210240       // float[128]
#define ZERO_BYTES   210752
#define OFF_ADJ      210752       // ushort[50000*96] = 9.6MB bucketed adjacency
#define OFF_X1F      9810816      // fp8[50000*128] rows 128B-aligned (6.4MB)
#define OFF_H1       16210816     // float[50000*100] relu layer1 (20MB)
#define OFF_X2B      36210816     // bf16[50000*32] rows 64B (3.2MB)
// end: 39410816 (~39MB)

typedef float v2f __attribute__((ext_vector_type(2)));

// ---- bf16 helpers ---------------------------------------------------------
__device__ __forceinline__ unsigned short f2bf(float x) {      // RNE
    unsigned int v = __float_as_uint(x);
    return (unsigned short)((v + 0x7FFFu + ((v >> 16) & 1u)) >> 16);
}
__device__ __forceinline__ float bflo(unsigned int u) { return __uint_as_float(u << 16); }
__device__ __forceinline__ float bfhi(unsigned int u) { return __uint_as_float(u & 0xFFFF0000u); }

// ---- bucketed fill: adj[d*96 + pos] = src; cnt[d] ends as deg[d] ----------
__global__ void k_fill(const int* __restrict__ src, const int* __restrict__ dst,
                       int* __restrict__ cnt, unsigned short* __restrict__ adj) {
    const int i = blockIdx.x * 256 + threadIdx.x;
    if (i >= NE) return;
    const int d = dst[i];
    const int p = atomicAdd(&cnt[d], 1);
    if (p < BSTRIDE) adj[d * BSTRIDE + p] = (unsigned short)src[i];
}

// ---- X1f = fp8_e4m3(feat @ W1)  (50000x128 @ 128x100), row = 128 fp8 -----
// Register-tiled: thread = 4 nodes x 4 cols; the 4 cols pack into one uint.
__global__ __launch_bounds__(256) void k_gemm1(const float4* __restrict__ feat4,
                                               const float* __restrict__ W1,
                                               unsigned int* __restrict__ X1f) {
    const int t = threadIdx.x;
    if (t >= 250) return;
    const int cg = t % 25;            // cols [4cg, 4cg+4)
    const int nq = t / 25;            // node quad within block
    const int node0 = blockIdx.x * 40 + nq * 4;
    const int col0 = cg * 4;

    float acc[4][4];
#pragma unroll
    for (int i = 0; i < 4; ++i)
#pragma unroll
        for (int j = 0; j < 4; ++j) acc[i][j] = 0.f;

    for (int k4 = 0; k4 < 32; ++k4) {
        float4 f[4];
#pragma unroll
        for (int i = 0; i < 4; ++i) f[i] = feat4[(node0 + i) * 32 + k4];
        float4 wr[4];
#pragma unroll
        for (int kk = 0; kk < 4; ++kk)
            wr[kk] = *(const float4*)(W1 + (k4 * 4 + kk) * 100 + col0);
#pragma unroll
        for (int kk = 0; kk < 4; ++kk) {
#pragma unroll
            for (int i = 0; i < 4; ++i) {
                const float fv = (kk == 0) ? f[i].x
                               : (kk == 1) ? f[i].y
                               : (kk == 2) ? f[i].z : f[i].w;
                acc[i][0] += fv * wr[kk].x;
                acc[i][1] += fv * wr[kk].y;
                acc[i][2] += fv * wr[kk].z;
                acc[i][3] += fv * wr[kk].w;
            }
        }
    }
#pragma unroll
    for (int i = 0; i < 4; ++i) {
        int u = 0;
        u = __builtin_amdgcn_cvt_pk_fp8_f32(acc[i][0], acc[i][1], u, false);
        u = __builtin_amdgcn_cvt_pk_fp8_f32(acc[i][2], acc[i][3], u, true);
        X1f[(node0 + i) * 32 + cg] = (unsigned int)u;
        if (cg == 24) {  // zero pad cols 100..127 (uints 25..31)
#pragma unroll
            for (int z = 25; z < 32; ++z) X1f[(node0 + i) * 32 + z] = 0u;
        }
    }
}

// ---- layer-1 aggregate: H1 = relu(where(deg>0, mean(fp8row), fp8row)+b1) --
// 7 lanes/node, lane q loads 16B (16 fp8) of the 128B row: exactly ONE
// 128B line per edge-row. Serial edge loop (R3/R5: unroll regresses).
__global__ void k_agg1(const uint4* __restrict__ X1u, const int* __restrict__ cnt,
                       const unsigned short* __restrict__ adj,
                       const float* __restrict__ b1, float* __restrict__ H1) {
    int tid = blockIdx.x * blockDim.x + threadIdx.x;
    if (tid >= NN * 7) return;
    const int node = tid / 7;
    const int q = tid - node * 7;        // cols [16q, 16q+16)
    const int d = cnt[node];
    const unsigned short* ab = adj + node * BSTRIDE;
    float a[16];
#pragma unroll
    for (int j = 0; j < 16; ++j) a[j] = 0.f;

#define ACC4(UU, B) { v2f l_ = __builtin_amdgcn_cvt_pk_f32_fp8((int)(UU), false); \
                      v2f h_ = __builtin_amdgcn_cvt_pk_f32_fp8((int)(UU), true);  \
                      a[B+0] += l_.x; a[B+1] += l_.y; a[B+2] += h_.x; a[B+3] += h_.y; }
#define SET4(UU, B) { v2f l_ = __builtin_amdgcn_cvt_pk_f32_fp8((int)(UU), false); \
                      v2f h_ = __builtin_amdgcn_cvt_pk_f32_fp8((int)(UU), true);  \
                      a[B+0] = l_.x; a[B+1] = l_.y; a[B+2] = h_.x; a[B+3] = h_.y; }

    for (int i = 0; i < d; ++i) {
        const int s = (int)ab[i];           // broadcast across the 7-lane group
        const uint4 u = X1u[s * 8 + q];     // 16B of the 128B row (1 line/edge)
        ACC4(u.x, 0) ACC4(u.y, 4) ACC4(u.z, 8) ACC4(u.w, 12)
    }
    if (d > 0) {
        const float inv = 1.f / (float)d;
#pragma unroll
        for (int j = 0; j < 16; ++j) a[j] *= inv;
    } else {
        const uint4 u = X1u[node * 8 + q];
        SET4(u.x, 0) SET4(u.y, 4) SET4(u.z, 8) SET4(u.w, 12)
    }
    const int col0 = 16 * q;
    float* hrow = H1 + node * 100 + col0;
    if (q < 6) {
#pragma unroll
        for (int v = 0; v < 4; ++v) {
            float4 r;
            r.x = fmaxf(a[4 * v + 0] + b1[col0 + 4 * v + 0], 0.f);
            r.y = fmaxf(a[4 * v + 1] + b1[col0 + 4 * v + 1], 0.f);
            r.z = fmaxf(a[4 * v + 2] + b1[col0 + 4 * v + 2], 0.f);
            r.w = fmaxf(a[4 * v + 3] + b1[col0 + 4 * v + 3], 0.f);
            *(float4*)(hrow + 4 * v) = r;
        }
    } else {  // q==6: cols 96..99 only
        float4 r;
        r.x = fmaxf(a[0] + b1[96], 0.f);
        r.y = fmaxf(a[1] + b1[97], 0.f);
        r.z = fmaxf(a[2] + b1[98], 0.f);
        r.w = fmaxf(a[3] + b1[99], 0.f);
        *(float4*)hrow = r;
    }
#undef ACC4
#undef SET4
}

// ---- X2b = bf16(H1 @ W2)  (50000x100 @ 100x20), row = 32 bf16 (64B) ------
__global__ void k_gemm2(const float* __restrict__ H1, const float* __restrict__ W2,
                        unsigned int* __restrict__ X2b) {
    int tid = blockIdx.x * blockDim.x + threadIdx.x;
    if (tid >= NN * 16) return;
    const int node = tid >> 4;
    const int j = tid & 15;
    if (j < 10) {
        const float* h = H1 + node * 100;
        float a0 = 0.f, a1 = 0.f;
#pragma unroll 5
        for (int k = 0; k < 100; ++k) {
            const float hv = h[k];
            a0 += hv * W2[k * 20 + 2 * j];
            a1 += hv * W2[k * 20 + 2 * j + 1];
        }
        X2b[tid] = (unsigned int)f2bf(a0) | ((unsigned int)f2bf(a1) << 16);
    } else {
        X2b[tid] = 0u;
    }
}

// ---- layer-2 aggregate + LDS per-graph reduce -----------------------------
__global__ __launch_bounds__(320) void k_agg2(const uint2* __restrict__ X2v,
                                              const int* __restrict__ cnt,
                                              const unsigned short* __restrict__ adj,
                                              const float* __restrict__ b2,
                                              const int* __restrict__ graph_id,
                                              float* __restrict__ g_sum,
                                              float* __restrict__ g_cnt) {
    __shared__ float lsum[NG * 20];
    __shared__ float lcnt[NG];
    const int t = threadIdx.x;
    for (int i = t; i < NG * 20; i += 320) lsum[i] = 0.f;
    for (int i = t; i < NG; i += 320) lcnt[i] = 0.f;
    __syncthreads();

    const int node = blockIdx.x * 64 + t / 5;
    const int q = t % 5;                      // cols [4q, 4q+4)
    if (node < NN) {
        const int d = cnt[node];
        const unsigned short* ab = adj + node * BSTRIDE;
        float ax = 0.f, ay = 0.f, az = 0.f, aw = 0.f;
        for (int i = 0; i < d; ++i) {
            const int s = (int)ab[i];
            const uint2 u = X2v[s * 8 + q];   // 8B of the 64B bf16 row
            ax += bflo(u.x); ay += bfhi(u.x);
            az += bflo(u.y); aw += bfhi(u.y);
        }
        if (d > 0) {
            const float inv = 1.f / (float)d;
            ax *= inv; ay *= inv; az *= inv; aw *= inv;
        } else {
            const uint2 u = X2v[node * 8 + q];
            ax = bflo(u.x); ay = bfhi(u.x);
            az = bflo(u.y); aw = bfhi(u.y);
        }
        const int col0 = 4 * q;
        const float hx = fmaxf(ax + b2[col0 + 0], 0.f);
        const float hy = fmaxf(ay + b2[col0 + 1], 0.f);
        const float hz = fmaxf(az + b2[col0 + 2], 0.f);
        const float hw = fmaxf(aw + b2[col0 + 3], 0.f);
        const int g = graph_id[node];
        atomicAdd(&lsum[g * 20 + col0 + 0], hx);
        atomicAdd(&lsum[g * 20 + col0 + 1], hy);
        atomicAdd(&lsum[g * 20 + col0 + 2], hz);
        atomicAdd(&lsum[g * 20 + col0 + 3], hw);
        if (q == 0) atomicAdd(&lcnt[g], 1.f);
    }
    __syncthreads();

    const int first = blockIdx.x * 64;
    const int last = min(first + 63, NN - 1);
    const int gmin = graph_id[first];
    const int span = graph_id[last] - gmin + 1;
    for (int idx = t; idx < span * 20; idx += 320) {
        const int g = gmin + idx / 20;
        const int c = idx - (idx / 20) * 20;
        const float v = lsum[g * 20 + c];
        if (v != 0.f) atomicAdd(&g_sum[g * 20 + c], v);
    }
    for (int idx = t; idx < span; idx += 320) {
        const float v = lcnt[gmin + idx];
        if (v != 0.f) atomicAdd(&g_cnt[gmin + idx], v);
    }
}

// ---- final: hg = g_sum/max(cnt,1); out = relu([hg,self]@Wf1+bf1)@Wf2+bf2 --
__global__ __launch_bounds__(128) void k_final(const float* __restrict__ g_sum,
                                               const float* __restrict__ g_cnt,
                                               const float* __restrict__ self_feat,
                                               const float* __restrict__ Wf1,
                                               const float* __restrict__ bf1,
                                               const float* __restrict__ Wf2,
                                               const float* __restrict__ bf2,
                                               float* __restrict__ out) {
    const int g = threadIdx.x;  // 128 graphs, one block
    float fused[36];
    const float cnt = fmaxf(g_cnt[g], 1.f);
    const float inv = 1.f / cnt;
#pragma unroll
    for (int j = 0; j < 20; ++j) fused[j] = g_sum[g * 20 + j] * inv;
#pragma unroll
    for (int j = 0; j < 16; ++j) fused[20 + j] = self_feat[g * 16 + j];
    float o = bf2[0];
#pragma unroll
    for (int i = 0; i < 10; ++i) {
        float t = bf1[i];
#pragma unroll
        for (int k = 0; k < 36; ++k) t += fused[k] * Wf1[k * 10 + i];
        o += fmaxf(t, 0.f) * Wf2[i];
    }
    out[g] = o;
}

extern "C" void kernel_launch(void* const* d_in, const int* in_sizes, int n_in,
                              void* d_out, int out_size, void* d_ws, size_t ws_size,
                              hipStream_t stream) {
    const float* feat      = (const float*)d_in[0];
    const float* self_feat = (const float*)d_in[1];
    const int*   src       = (const int*)d_in[2];
    const int*   dst       = (const int*)d_in[3];
    const int*   graph_id  = (const int*)d_in[4];
    const float* W1        = (const float*)d_in[5];
    const float* b1        = (const float*)d_in[6];
    const float* W2        = (const float*)d_in[7];
    const float* b2        = (const float*)d_in[8];
    const float* Wf1       = (const float*)d_in[9];
    const float* bf1       = (const float*)d_in[10];
    const float* Wf2       = (const float*)d_in[11];
    const float* bf2       = (const float*)d_in[12];

    char* w = (char*)d_ws;
    int*            cnt      = (int*)(w + OFF_CNT);
    float*          g_sum    = (float*)(w + OFF_GSUM);
    float*          g_cnt    = (float*)(w + OFF_GCNT);
    unsigned short* adj      = (unsigned short*)(w + OFF_ADJ);
    unsigned int*   X1f      = (unsigned int*)(w + OFF_X1F);
    float*          H1       = (float*)(w + OFF_H1);
    unsigned int*   X2b      = (unsigned int*)(w + OFF_X2B);

    hipMemsetAsync(w, 0, ZERO_BYTES, stream);  // cnt + g_sum + g_cnt

    k_fill<<<(NE + 255) / 256, 256, 0, stream>>>(src, dst, cnt, adj);
    k_gemm1<<<1250, 256, 0, stream>>>((const float4*)feat, W1, X1f);
    k_agg1<<<(NN * 7 + 255) / 256, 256, 0, stream>>>((const uint4*)X1f, cnt,
                                                     adj, b1, H1);
    k_gemm2<<<(NN * 16 + 255) / 256, 256, 0, stream>>>(H1, W2, X2b);
    k_agg2<<<(NN + 63) / 64, 320, 0, stream>>>((const uint2*)X2b, cnt,
                                               adj, b2, graph_id, g_sum, g_cnt);
    k_final<<<1, 128, 0, stream>>>(g_sum, g_cnt, self_feat, Wf1, bf1, Wf2, bf2,
                                   (float*)d_out);
}

// Round 9
// 332.177 us; speedup vs baseline: 2.3802x; 1.1421x over previous
//
#include <hip/hip_runtime.h>

constexpr int NN = 50000;    // nodes
constexpr int NE = 1600000;  // edges
constexpr int NG = 128;      // graphs
constexpr int BSTRIDE = 96;  // adj bucket slots per node (deg~Poisson(32), max~58)

// k_fill: 8 concurrent dst-range passes, pass = blockIdx % 8 (XCD-aware:
// MI355X dispatches blocks round-robin over 8 XCDs, so each dst range's
// cursor lines + adj slice stay XCD-local in L2. Perf heuristic only;
// correctness holds under any block->XCD mapping.)
constexpr int FILL_PASSES = 8;
constexpr int NODES_PER_PASS = 6250;              // 8*6250 = 50000
constexpr int BLOCKS_PER_PASS = (NE + 255) / 256; // 6250

// workspace layout (bytes)
#define OFF_CNT      0            // int[50000] atomic cursor; == deg after fill
#define OFF_GSUM     200000       // float[128*20]
#define OFF_GCNT     210240       // float[128]
#define ZERO_BYTES   210752
#define OFF_ADJ      210752       // ushort[50000*96] = 9.6MB bucketed adjacency
#define OFF_X1F      9810816      // fp8[50000*128] rows 128B-aligned (6.4MB)
#define OFF_H1       16210816     // float[50000*100] relu layer1 (20MB)
#define OFF_X2B      36210816     // bf16[50000*32] rows 64B (3.2MB)
// end: 39410816 (~39MB)

typedef float v2f __attribute__((ext_vector_type(2)));

// ---- bf16 helpers ---------------------------------------------------------
__device__ __forceinline__ unsigned short f2bf(float x) {      // RNE
    unsigned int v = __float_as_uint(x);
    return (unsigned short)((v + 0x7FFFu + ((v >> 16) & 1u)) >> 16);
}
__device__ __forceinline__ float bflo(unsigned int u) { return __uint_as_float(u << 16); }
__device__ __forceinline__ float bfhi(unsigned int u) { return __uint_as_float(u & 0xFFFF0000u); }

// ---- bucketed fill, XCD-aware dst-range passes ----------------------------
// pass p handles dst in [p*6250, (p+1)*6250): adj slice 1.2MB + cursor slice
// 25KB per pass stay L2-resident on one XCD -> merged full-line writebacks
// instead of 64B fragments (R5/R8 lesson: scattered 2B stores cost ~100MB).
__global__ void k_fill(const int* __restrict__ src, const int* __restrict__ dst,
                       int* __restrict__ cnt, unsigned short* __restrict__ adj) {
    const int pass = blockIdx.x & 7;          // XCD-aligned (round-robin dispatch)
    const int chunk = blockIdx.x >> 3;
    const int i = chunk * 256 + threadIdx.x;
    if (i >= NE) return;
    const int d = dst[i];
    const int lo = pass * NODES_PER_PASS;
    if (d >= lo && d < lo + NODES_PER_PASS) {
        const int p = atomicAdd(&cnt[d], 1);
        if (p < BSTRIDE) adj[d * BSTRIDE + p] = (unsigned short)src[i];
    }
}

// ---- X1f = fp8_e4m3(feat @ W1)  (50000x128 @ 128x100), row = 128 fp8 -----
// Register-tiled: thread = 4 nodes x 4 cols; the 4 cols pack into one uint.
__global__ __launch_bounds__(256) void k_gemm1(const float4* __restrict__ feat4,
                                               const float* __restrict__ W1,
                                               unsigned int* __restrict__ X1f) {
    const int t = threadIdx.x;
    if (t >= 250) return;
    const int cg = t % 25;            // cols [4cg, 4cg+4)
    const int nq = t / 25;            // node quad within block
    const int node0 = blockIdx.x * 40 + nq * 4;
    const int col0 = cg * 4;

    float acc[4][4];
#pragma unroll
    for (int i = 0; i < 4; ++i)
#pragma unroll
        for (int j = 0; j < 4; ++j) acc[i][j] = 0.f;

    for (int k4 = 0; k4 < 32; ++k4) {
        float4 f[4];
#pragma unroll
        for (int i = 0; i < 4; ++i) f[i] = feat4[(node0 + i) * 32 + k4];
        float4 wr[4];
#pragma unroll
        for (int kk = 0; kk < 4; ++kk)
            wr[kk] = *(const float4*)(W1 + (k4 * 4 + kk) * 100 + col0);
#pragma unroll
        for (int kk = 0; kk < 4; ++kk) {
#pragma unroll
            for (int i = 0; i < 4; ++i) {
                const float fv = (kk == 0) ? f[i].x
                               : (kk == 1) ? f[i].y
                               : (kk == 2) ? f[i].z : f[i].w;
                acc[i][0] += fv * wr[kk].x;
                acc[i][1] += fv * wr[kk].y;
                acc[i][2] += fv * wr[kk].z;
                acc[i][3] += fv * wr[kk].w;
            }
        }
    }
#pragma unroll
    for (int i = 0; i < 4; ++i) {
        int u = 0;
        u = __builtin_amdgcn_cvt_pk_fp8_f32(acc[i][0], acc[i][1], u, false);
        u = __builtin_amdgcn_cvt_pk_fp8_f32(acc[i][2], acc[i][3], u, true);
        X1f[(node0 + i) * 32 + cg] = (unsigned int)u;
        if (cg == 24) {  // zero pad cols 100..127 (uints 25..31)
#pragma unroll
            for (int z = 25; z < 32; ++z) X1f[(node0 + i) * 32 + z] = 0u;
        }
    }
}

// ---- layer-1 aggregate: H1 = relu(where(deg>0, mean(fp8row), fp8row)+b1) --
// 7 lanes/node, lane q loads 16B (16 fp8) of the 128B row: exactly ONE
// 128B line per edge-row. Serial edge loop (R3/R5: unroll regresses).
__global__ void k_agg1(const uint4* __restrict__ X1u, const int* __restrict__ cnt,
                       const unsigned short* __restrict__ adj,
                       const float* __restrict__ b1, float* __restrict__ H1) {
    int tid = blockIdx.x * blockDim.x + threadIdx.x;
    if (tid >= NN * 7) return;
    const int node = tid / 7;
    const int q = tid - node * 7;        // cols [16q, 16q+16)
    const int d = cnt[node];
    const unsigned short* ab = adj + node * BSTRIDE;
    float a[16];
#pragma unroll
    for (int j = 0; j < 16; ++j) a[j] = 0.f;

#define ACC4(UU, B) { v2f l_ = __builtin_amdgcn_cvt_pk_f32_fp8((int)(UU), false); \
                      v2f h_ = __builtin_amdgcn_cvt_pk_f32_fp8((int)(UU), true);  \
                      a[B+0] += l_.x; a[B+1] += l_.y; a[B+2] += h_.x; a[B+3] += h_.y; }
#define SET4(UU, B) { v2f l_ = __builtin_amdgcn_cvt_pk_f32_fp8((int)(UU), false); \
                      v2f h_ = __builtin_amdgcn_cvt_pk_f32_fp8((int)(UU), true);  \
                      a[B+0] = l_.x; a[B+1] = l_.y; a[B+2] = h_.x; a[B+3] = h_.y; }

    for (int i = 0; i < d; ++i) {
        const int s = (int)ab[i];           // broadcast across the 7-lane group
        const uint4 u = X1u[s * 8 + q];     // 16B of the 128B row (1 line/edge)
        ACC4(u.x, 0) ACC4(u.y, 4) ACC4(u.z, 8) ACC4(u.w, 12)
    }
    if (d > 0) {
        const float inv = 1.f / (float)d;
#pragma unroll
        for (int j = 0; j < 16; ++j) a[j] *= inv;
    } else {
        const uint4 u = X1u[node * 8 + q];
        SET4(u.x, 0) SET4(u.y, 4) SET4(u.z, 8) SET4(u.w, 12)
    }
    const int col0 = 16 * q;
    float* hrow = H1 + node * 100 + col0;
    if (q < 6) {
#pragma unroll
        for (int v = 0; v < 4; ++v) {
            float4 r;
            r.x = fmaxf(a[4 * v + 0] + b1[col0 + 4 * v + 0], 0.f);
            r.y = fmaxf(a[4 * v + 1] + b1[col0 + 4 * v + 1], 0.f);
            r.z = fmaxf(a[4 * v + 2] + b1[col0 + 4 * v + 2], 0.f);
            r.w = fmaxf(a[4 * v + 3] + b1[col0 + 4 * v + 3], 0.f);
            *(float4*)(hrow + 4 * v) = r;
        }
    } else {  // q==6: cols 96..99 only
        float4 r;
        r.x = fmaxf(a[0] + b1[96], 0.f);
        r.y = fmaxf(a[1] + b1[97], 0.f);
        r.z = fmaxf(a[2] + b1[98], 0.f);
        r.w = fmaxf(a[3] + b1[99], 0.f);
        *(float4*)hrow = r;
    }
#undef ACC4
#undef SET4
}

// ---- X2b = bf16(H1 @ W2)  (50000x100 @ 100x20), row = 32 bf16 (64B) ------
__global__ void k_gemm2(const float* __restrict__ H1, const float* __restrict__ W2,
                        unsigned int* __restrict__ X2b) {
    int tid = blockIdx.x * blockDim.x + threadIdx.x;
    if (tid >= NN * 16) return;
    const int node = tid >> 4;
    const int j = tid & 15;
    if (j < 10) {
        const float* h = H1 + node * 100;
        float a0 = 0.f, a1 = 0.f;
#pragma unroll 5
        for (int k = 0; k < 100; ++k) {
            const float hv = h[k];
            a0 += hv * W2[k * 20 + 2 * j];
            a1 += hv * W2[k * 20 + 2 * j + 1];
        }
        X2b[tid] = (unsigned int)f2bf(a0) | ((unsigned int)f2bf(a1) << 16);
    } else {
        X2b[tid] = 0u;
    }
}

// ---- layer-2 aggregate + LDS per-graph reduce -----------------------------
__global__ __launch_bounds__(320) void k_agg2(const uint2* __restrict__ X2v,
                                              const int* __restrict__ cnt,
                                              const unsigned short* __restrict__ adj,
                                              const float* __restrict__ b2,
                                              const int* __restrict__ graph_id,
                                              float* __restrict__ g_sum,
                                              float* __restrict__ g_cnt) {
    __shared__ float lsum[NG * 20];
    __shared__ float lcnt[NG];
    const int t = threadIdx.x;
    for (int i = t; i < NG * 20; i += 320) lsum[i] = 0.f;
    for (int i = t; i < NG; i += 320) lcnt[i] = 0.f;
    __syncthreads();

    const int node = blockIdx.x * 64 + t / 5;
    const int q = t % 5;                      // cols [4q, 4q+4)
    if (node < NN) {
        const int d = cnt[node];
        const unsigned short* ab = adj + node * BSTRIDE;
        float ax = 0.f, ay = 0.f, az = 0.f, aw = 0.f;
        for (int i = 0; i < d; ++i) {
            const int s = (int)ab[i];
            const uint2 u = X2v[s * 8 + q];   // 8B of the 64B bf16 row
            ax += bflo(u.x); ay += bfhi(u.x);
            az += bflo(u.y); aw += bfhi(u.y);
        }
        if (d > 0) {
            const float inv = 1.f / (float)d;
            ax *= inv; ay *= inv; az *= inv; aw *= inv;
        } else {
            const uint2 u = X2v[node * 8 + q];
            ax = bflo(u.x); ay = bfhi(u.x);
            az = bflo(u.y); aw = bfhi(u.y);
        }
        const int col0 = 4 * q;
        const float hx = fmaxf(ax + b2[col0 + 0], 0.f);
        const float hy = fmaxf(ay + b2[col0 + 1], 0.f);
        const float hz = fmaxf(az + b2[col0 + 2], 0.f);
        const float hw = fmaxf(aw + b2[col0 + 3], 0.f);
        const int g = graph_id[node];
        atomicAdd(&lsum[g * 20 + col0 + 0], hx);
        atomicAdd(&lsum[g * 20 + col0 + 1], hy);
        atomicAdd(&lsum[g * 20 + col0 + 2], hz);
        atomicAdd(&lsum[g * 20 + col0 + 3], hw);
        if (q == 0) atomicAdd(&lcnt[g], 1.f);
    }
    __syncthreads();

    const int first = blockIdx.x * 64;
    const int last = min(first + 63, NN - 1);
    const int gmin = graph_id[first];
    const int span = graph_id[last] - gmin + 1;
    for (int idx = t; idx < span * 20; idx += 320) {
        const int g = gmin + idx / 20;
        const int c = idx - (idx / 20) * 20;
        const float v = lsum[g * 20 + c];
        if (v != 0.f) atomicAdd(&g_sum[g * 20 + c], v);
    }
    for (int idx = t; idx < span; idx += 320) {
        const float v = lcnt[gmin + idx];
        if (v != 0.f) atomicAdd(&g_cnt[gmin + idx], v);
    }
}

// ---- final: hg = g_sum/max(cnt,1); out = relu([hg,self]@Wf1+bf1)@Wf2+bf2 --
__global__ __launch_bounds__(128) void k_final(const float* __restrict__ g_sum,
                                               const float* __restrict__ g_cnt,
                                               const float* __restrict__ self_feat,
                                               const float* __restrict__ Wf1,
                                               const float* __restrict__ bf1,
                                               const float* __restrict__ Wf2,
                                               const float* __restrict__ bf2,
                                               float* __restrict__ out) {
    const int g = threadIdx.x;  // 128 graphs, one block
    float fused[36];
    const float cnt = fmaxf(g_cnt[g], 1.f);
    const float inv = 1.f / cnt;
#pragma unroll
    for (int j = 0; j < 20; ++j) fused[j] = g_sum[g * 20 + j] * inv;
#pragma unroll
    for (int j = 0; j < 16; ++j) fused[20 + j] = self_feat[g * 16 + j];
    float o = bf2[0];
#pragma unroll
    for (int i = 0; i < 10; ++i) {
        float t = bf1[i];
#pragma unroll
        for (int k = 0; k < 36; ++k) t += fused[k] * Wf1[k * 10 + i];
        o += fmaxf(t, 0.f) * Wf2[i];
    }
    out[g] = o;
}

extern "C" void kernel_launch(void* const* d_in, const int* in_sizes, int n_in,
                              void* d_out, int out_size, void* d_ws, size_t ws_size,
                              hipStream_t stream) {
    const float* feat      = (const float*)d_in[0];
    const float* self_feat = (const float*)d_in[1];
    const int*   src       = (const int*)d_in[2];
    const int*   dst       = (const int*)d_in[3];
    const int*   graph_id  = (const int*)d_in[4];
    const float* W1        = (const float*)d_in[5];
    const float* b1        = (const float*)d_in[6];
    const float* W2        = (const float*)d_in[7];
    const float* b2        = (const float*)d_in[8];
    const float* Wf1       = (const float*)d_in[9];
    const float* bf1       = (const float*)d_in[10];
    const float* Wf2       = (const float*)d_in[11];
    const float* bf2       = (const float*)d_in[12];

    char* w = (char*)d_ws;
    int*            cnt      = (int*)(w + OFF_CNT);
    float*          g_sum    = (float*)(w + OFF_GSUM);
    float*          g_cnt    = (float*)(w + OFF_GCNT);
    unsigned short* adj      = (unsigned short*)(w + OFF_ADJ);
    unsigned int*   X1f      = (unsigned int*)(w + OFF_X1F);
    float*          H1       = (float*)(w + OFF_H1);
    unsigned int*   X2b      = (unsigned int*)(w + OFF_X2B);

    hipMemsetAsync(w, 0, ZERO_BYTES, stream);  // cnt + g_sum + g_cnt

    k_fill<<<FILL_PASSES * BLOCKS_PER_PASS, 256, 0, stream>>>(src, dst, cnt, adj);
    k_gemm1<<<1250, 256, 0, stream>>>((const float4*)feat, W1, X1f);
    k_agg1<<<(NN * 7 + 255) / 256, 256, 0, stream>>>((const uint4*)X1f, cnt,
                                                     adj, b1, H1);
    k_gemm2<<<(NN * 16 + 255) / 256, 256, 0, stream>>>(H1, W2, X2b);
    k_agg2<<<(NN + 63) / 64, 320, 0, stream>>>((const uint2*)X2b, cnt,
                                               adj, b2, graph_id, g_sum, g_cnt);
    k_final<<<1, 128, 0, stream>>>(g_sum, g_cnt, self_feat, Wf1, bf1, Wf2, bf2,
                                   (float*)d_out);
}